// Round 7
// baseline (1802.834 us; speedup 1.0000x reference)
//
#include <hip/hip_runtime.h>
#include <math.h>

typedef unsigned long long u64;
typedef unsigned int u32;

#define HH 160
#define WW 160
#define CC 256
#define NPX 25600
#define NA 9
#define NSC 230400
#define K_SEL 6000
#define SEL_PAD 6016
#define IMS 2560.0f
#define DWH 4.135166556742356f

struct SelState { u64 prefix; u32 r; u32 cnt; };

// ---- ws layout (bytes) ----
#define OFF_BOXES   0u               // float4[230400] -> 3,686,400
#define OFF_SCORES  3686400u         // float [230400]
#define OFF_KEYS    4608000u         // u64   [230400]
#define OFF_STATE   7499776u
#define OFF_SELK    7500032u         // u64[6016]
#define OFF_SX1     7548160u
#define OFF_SY1     7572224u
#define OFF_SX2     7596288u
#define OFF_SY2     7620352u
#define OFF_SSC     7644416u
#define OFF_ALIVE   7668480u
#define OFF_MASKT   11503104u        // u64[94*6016 + 128 pad] -> ends 16,028,160
#define OFF_RPN     27869184u        // float[256*160*160] -> ends 54,083,584

__constant__ float c_bx1[9] = {-91.f,-181.f,-362.f,-64.f,-128.f,-256.f,-45.f,-91.f,-181.f};
__constant__ float c_by1[9] = {-45.f,-91.f,-181.f,-64.f,-128.f,-256.f,-91.f,-181.f,-362.f};
__constant__ float c_bx2[9] = { 91.f, 181.f, 362.f, 64.f, 128.f, 256.f, 45.f, 91.f, 181.f};
__constant__ float c_by2[9] = { 45.f,  91.f, 181.f, 64.f, 128.f, 256.f, 91.f, 181.f, 362.f};

__device__ inline u64 shfl64(u64 v, int src) {
  int lo = (int)(v & 0xFFFFFFFFull), hi = (int)(v >> 32);
  lo = __shfl(lo, src, 64); hi = __shfl(hi, src, 64);
  return ((u64)(u32)hi << 32) | (u32)lo;
}

// ---------------- 1. conv3x3 + bias + relu (implicit GEMM, fp32) ----------------
// grid 800 = 5 ct x 40 rt x 4 ot. Tile 64 oc x (4 rows x 32 cols).
// Thread: 8 oc x (1 row x 4 cols) = 32 acc. ps stride 36 -> all rows 16B aligned,
// (r+c)%8 16B-group mapping = conflict-free b128. Explicit component FMAs.
#define TAP8(A0, A1, B0, B1, B2, B3)                                        \
  acc[0][0] += A0.x * B0; acc[0][1] += A0.x * B1; acc[0][2] += A0.x * B2; acc[0][3] += A0.x * B3; \
  acc[1][0] += A0.y * B0; acc[1][1] += A0.y * B1; acc[1][2] += A0.y * B2; acc[1][3] += A0.y * B3; \
  acc[2][0] += A0.z * B0; acc[2][1] += A0.z * B1; acc[2][2] += A0.z * B2; acc[2][3] += A0.z * B3; \
  acc[3][0] += A0.w * B0; acc[3][1] += A0.w * B1; acc[3][2] += A0.w * B2; acc[3][3] += A0.w * B3; \
  acc[4][0] += A1.x * B0; acc[4][1] += A1.x * B1; acc[4][2] += A1.x * B2; acc[4][3] += A1.x * B3; \
  acc[5][0] += A1.y * B0; acc[5][1] += A1.y * B1; acc[5][2] += A1.y * B2; acc[5][3] += A1.y * B3; \
  acc[6][0] += A1.z * B0; acc[6][1] += A1.z * B1; acc[6][2] += A1.z * B2; acc[6][3] += A1.z * B3; \
  acc[7][0] += A1.w * B0; acc[7][1] += A1.w * B1; acc[7][2] += A1.w * B2; acc[7][3] += A1.w * B3;

__global__ __launch_bounds__(256) void conv_k(const float* __restrict__ feat,
                                              const float* __restrict__ w,
                                              const float* __restrict__ bias,
                                              float* __restrict__ outp) {
  int bx = blockIdx.x;            // 800 = 5 * 40 * 4
  int ct = bx % 5;
  int rt = (bx / 5) % 40;
  int ot = bx / 200;
  int x0 = ct * 32, y0 = rt * 4, oc0 = ot * 64;

  __shared__ float wsm[72][68];   // [k=icl*9+tap][oc], 16B-aligned rows
  __shared__ float ps[8][6][36];  // [icl][row][col], 16B-aligned rows

  int tid = threadIdx.x;
  int og = tid >> 5;              // 0..7 -> 8 oc each
  int pg = tid & 31;
  int row = pg >> 3;              // 0..3
  int col = (pg & 7) * 4;         // 0,4,...,28

  float acc[8][4];
#pragma unroll
  for (int i = 0; i < 8; i++)
#pragma unroll
    for (int j = 0; j < 4; j++) acc[i][j] = 0.f;

  for (int ic0 = 0; ic0 < CC; ic0 += 8) {
    __syncthreads();
    // stage weights: 64 oc x 72 k-values
    for (int idx = tid; idx < 4608; idx += 256) {
      int oc = idx / 72, j = idx % 72;
      wsm[j][oc] = w[(oc0 + oc) * 2304 + ic0 * 9 + j];
    }
    // stage pixels: 8 ic x 6 rows x 34 cols, zero-pad fused
    for (int it = 0; it < 7; it++) {
      int idx = tid + it * 256;
      if (idx < 1632) {
        int icl = idx / 204, rem = idx % 204;
        int r = rem / 34, c = rem % 34;
        int gy = y0 + r - 1, gx = x0 + c - 1;
        float v = 0.f;
        if ((unsigned)gy < 160u && (unsigned)gx < 160u)
          v = feat[(ic0 + icl) * NPX + gy * WW + gx];
        ps[icl][r][c] = v;
      }
    }
    __syncthreads();
#pragma unroll
    for (int icl = 0; icl < 8; icl++) {
#pragma unroll
      for (int dy = 0; dy < 3; dy++) {
        float4 b0 = *(const float4*)&ps[icl][row + dy][col];
        float2 b1 = *(const float2*)&ps[icl][row + dy][col + 4];
        {
          float4 a0 = *(const float4*)&wsm[icl * 9 + dy * 3 + 0][og * 8];
          float4 a1 = *(const float4*)&wsm[icl * 9 + dy * 3 + 0][og * 8 + 4];
          TAP8(a0, a1, b0.x, b0.y, b0.z, b0.w)
        }
        {
          float4 a0 = *(const float4*)&wsm[icl * 9 + dy * 3 + 1][og * 8];
          float4 a1 = *(const float4*)&wsm[icl * 9 + dy * 3 + 1][og * 8 + 4];
          TAP8(a0, a1, b0.y, b0.z, b0.w, b1.x)
        }
        {
          float4 a0 = *(const float4*)&wsm[icl * 9 + dy * 3 + 2][og * 8];
          float4 a1 = *(const float4*)&wsm[icl * 9 + dy * 3 + 2][og * 8 + 4];
          TAP8(a0, a1, b0.z, b0.w, b1.x, b1.y)
        }
      }
    }
  }
#pragma unroll
  for (int i = 0; i < 8; i++) {
    int oc = oc0 + og * 8 + i;
    float bv = bias[oc];
    float4 v;
    v.x = fmaxf(acc[i][0] + bv, 0.f);
    v.y = fmaxf(acc[i][1] + bv, 0.f);
    v.z = fmaxf(acc[i][2] + bv, 0.f);
    v.w = fmaxf(acc[i][3] + bv, 0.f);
    *(float4*)&outp[(size_t)oc * NPX + (y0 + row) * WW + x0 + col] = v;
  }
}

// ---------------- 2. heads + sigmoid + decode + clip + key ----------------
__global__ __launch_bounds__(256) void heads_k(const float* __restrict__ rpn,
                                               const float* __restrict__ cls_w,
                                               const float* __restrict__ cls_b,
                                               const float* __restrict__ bbox_w,
                                               const float* __restrict__ bbox_b,
                                               float4* __restrict__ boxes,
                                               float* __restrict__ scores,
                                               u64* __restrict__ keys) {
  __shared__ float sf[32][260];
  __shared__ float so[45][33];
  int tid = threadIdx.x;
  int px0 = blockIdx.x * 32;
  for (int idx = tid; idx < 8192; idx += 256) {
    int c = idx >> 5, p = idx & 31;
    sf[p][c] = rpn[(size_t)c * NPX + px0 + p];
  }
  __syncthreads();
  int p = tid & 31, g = tid >> 5;
  for (int oi = 0; oi < 6; oi++) {
    int o = g + oi * 8;
    if (o >= 45) break;
    const float* wr = (o < 9) ? (cls_w + o * CC) : (bbox_w + (o - 9) * CC);
    float bsum = (o < 9) ? cls_b[o] : bbox_b[o - 9];
    float s = 0.f;
    for (int c = 0; c < CC; c += 4) {
      float4 f = *(const float4*)&sf[p][c];
      float4 wv = *(const float4*)&wr[c];
      s += f.x * wv.x; s += f.y * wv.y; s += f.z * wv.z; s += f.w * wv.w;
    }
    so[o][p] = s + bsum;
  }
  __syncthreads();
  for (int t = tid; t < 288; t += 256) {
    int a = t >> 5, pp = t & 31;
    int px = px0 + pp;
    int y = px / 160, x = px - y * 160;
    float logit = so[a][pp];
    float sc = 1.f / (1.f + expf(-logit));
    float ddx = so[9 + 4 * a][pp], ddy = so[10 + 4 * a][pp];
    float ddw = fminf(so[11 + 4 * a][pp], DWH);
    float ddh = fminf(so[12 + 4 * a][pp], DWH);
    float ax1 = x * 16.f + c_bx1[a];
    float ay1 = y * 16.f + c_by1[a];
    float ax2 = x * 16.f + c_bx2[a];
    float ay2 = y * 16.f + c_by2[a];
    float aw = ax2 - ax1, ah = ay2 - ay1;
    float cx = ax1 + 0.5f * aw, cy = ay1 + 0.5f * ah;
    float pcx = ddx * aw + cx, pcy = ddy * ah + cy;
    float pw = expf(ddw) * aw, phh = expf(ddh) * ah;
    float x1 = pcx - 0.5f * pw, y1 = pcy - 0.5f * phh;
    float x2 = pcx + 0.5f * pw, y2 = pcy + 0.5f * phh;
    x1 = fminf(fmaxf(x1, 0.f), IMS); x2 = fminf(fmaxf(x2, 0.f), IMS);
    y1 = fminf(fmaxf(y1, 0.f), IMS); y2 = fminf(fmaxf(y2, 0.f), IMS);
    int gidx = px * 9 + a;
    boxes[gidx] = make_float4(x1, y1, x2, y2);
    scores[gidx] = sc;
    u32 sb = __float_as_uint(sc);
    u32 mono = (sb & 0x80000000u) ? ~sb : (sb | 0x80000000u);
    keys[gidx] = ((u64)mono << 32) | (u64)(0xFFFFFFFFu - (u32)gidx);
  }
}

// ---------------- 3. single-block radix select (batched LDS atomics) ----------------
__global__ __launch_bounds__(1024) void select_k(const u64* __restrict__ keys, SelState* st) {
  __shared__ u32 hist[8192];
  __shared__ u32 tsum[1024];
  __shared__ u32 wsum[16];
  __shared__ u64 sprefix;
  __shared__ u32 sr;
  int tid = threadIdx.x;
  int lane = tid & 63, wv = tid >> 6;
  u64 prefix = 0;
  u32 r = K_SEL;
  int bitsdone = 0;
  const int widths[5] = {13, 13, 13, 13, 12};

  for (int pass = 0; pass < 5; pass++) {
    int wbits = widths[pass];
    int nbins = 1 << wbits;
    int shift = 64 - bitsdone - wbits;
    for (int i = tid; i < nbins; i += 1024) hist[i] = 0;
    __syncthreads();

    u32 run_d = 0xFFFFFFFFu, run_c = 0;   // lane-0 digit-run accumulator

#define PROC(kk)                                                            \
    {                                                                       \
      bool active = (bitsdone == 0) || (((kk) >> (64 - bitsdone)) == prefix); \
      u32 digit = (u32)(((kk) >> shift) & (u64)(nbins - 1));                \
      u64 act = __ballot(active);                                           \
      bool done = false;                                                    \
      if (act == ~0ull) {                                                   \
        u32 d0 = (u32)__shfl((int)digit, 0, 64);                            \
        if (__ballot(digit == d0) == ~0ull) {                               \
          if (lane == 0) {                                                  \
            if (d0 == run_d) run_c += 64u;                                  \
            else {                                                          \
              if (run_c) atomicAdd(&hist[run_d], run_c);                    \
              run_d = d0; run_c = 64u;                                      \
            }                                                               \
          }                                                                 \
          done = true;                                                      \
        }                                                                   \
      }                                                                     \
      if (!done && active) atomicAdd(&hist[digit], 1u);                     \
    }

    int i = tid;
    for (int it = 0; it < 56; it++, i += 4096) {
      u64 k0 = keys[i];
      u64 k1 = keys[i + 1024];
      u64 k2 = keys[i + 2048];
      u64 k3 = keys[i + 3072];
      PROC(k0) PROC(k1) PROC(k2) PROC(k3)
    }
    { u64 k4 = keys[i]; PROC(k4) }   // covers 230400
#undef PROC
    if (lane == 0 && run_c) atomicAdd(&hist[run_d], run_c);
    __syncthreads();

    int bpt = nbins >> 10;
    u32 s = 0;
    for (int b = 0; b < bpt; b++) s += hist[tid * bpt + b];
    tsum[tid] = s;
    u32 v = s;
#pragma unroll
    for (int off = 1; off < 64; off <<= 1) v += (u32)__shfl_xor((int)v, off, 64);
    if (lane == 0) wsum[wv] = v;
    __syncthreads();

    if (tid == 0) {
      u32 cum = 0;
      int ws = 15;
      while (ws > 0 && cum + wsum[ws] < r) { cum += wsum[ws]; ws--; }
      int t = ws * 64 + 63, tend = ws * 64;
      while (t > tend && cum + tsum[t] < r) { cum += tsum[t]; t--; }
      int b = t * bpt + bpt - 1, bend = t * bpt;
      while (b > bend && cum + hist[b] < r) { cum += hist[b]; b--; }
      sprefix = (prefix << wbits) | (u64)(u32)b;
      sr = r - cum;
    }
    __syncthreads();
    prefix = sprefix;
    r = sr;
    bitsdone += wbits;
    __syncthreads();
  }
  if (tid == 0) {
    st->prefix = prefix;
    st->r = r;
    st->cnt = 0;
  }
}

__global__ __launch_bounds__(256) void compact_k(const u64* __restrict__ keys,
                                                 SelState* st, u64* __restrict__ selk) {
  int idx = blockIdx.x * 256 + threadIdx.x;
  u64 k = keys[idx];
  if (k >= st->prefix) {
    u32 pos = atomicAdd(&st->cnt, 1u);
    selk[pos] = k;
  }
}

// ---------------- 4. exact rank -> sorted SoA ----------------
__global__ __launch_bounds__(64) void rank_k(const u64* __restrict__ selk,
                                             const float4* __restrict__ boxes,
                                             const float* __restrict__ scores,
                                             float* sx1, float* sy1, float* sx2, float* sy2, float* ssc) {
  __shared__ __align__(16) u64 sk[SEL_PAD];
  int lane = threadIdx.x;
  for (int i = lane; i < SEL_PAD; i += 64) sk[i] = (i < K_SEL) ? selk[i] : 0ull;
  __syncthreads();
  int n = blockIdx.x * 64 + lane;
  u64 myk = (n < K_SEL) ? selk[n] : ~0ull;
  int cnt = 0;
  const ulonglong2* sk2 = (const ulonglong2*)sk;
  for (int j = 0; j < SEL_PAD / 2; j++) {
    ulonglong2 kk = sk2[j];
    cnt += (kk.x > myk) ? 1 : 0;
    cnt += (kk.y > myk) ? 1 : 0;
  }
  if (n < K_SEL) {
    u32 oidx = 0xFFFFFFFFu - (u32)(myk & 0xFFFFFFFFull);
    float4 b = boxes[oidx];
    sx1[cnt] = b.x; sy1[cnt] = b.y; sx2[cnt] = b.z; sy2[cnt] = b.w;
    ssc[cnt] = scores[oidx];
  }
}

// ---------------- 5. pairwise suppression mask (column-major) ----------------
__global__ __launch_bounds__(256) void mask_k(const float* __restrict__ sx1, const float* __restrict__ sy1,
                                              const float* __restrict__ sx2, const float* __restrict__ sy2,
                                              u64* __restrict__ maskT) {
  __shared__ float jb[5][3008];
  int tid = threadIdx.x;
  int wv = tid >> 6, lane = tid & 63;
  int ibase = blockIdx.x * 32 + wv * 8;
  float ix1[8], iy1[8], ix2[8], iy2[8], ia[8];
#pragma unroll
  for (int r = 0; r < 8; r++) {
    int i = ibase + r;
    ix1[r] = sx1[i]; iy1[r] = sy1[i]; ix2[r] = sx2[i]; iy2[r] = sy2[i];
    ia[r] = (ix2[r] - ix1[r]) * (iy2[r] - iy1[r]);
  }
  for (int half = 0; half < 2; half++) {
    int j0 = half * 3008;
    __syncthreads();
    for (int idx = tid; idx < 3008; idx += 256) {
      int j = j0 + idx;
      bool v = j < K_SEL;
      float a = v ? sx1[j] : 0.f;
      float b = v ? sy1[j] : 0.f;
      float c = v ? sx2[j] : 0.f;
      float d = v ? sy2[j] : 0.f;
      jb[0][idx] = a; jb[1][idx] = b; jb[2][idx] = c; jb[3][idx] = d;
      jb[4][idx] = (c - a) * (d - b);
    }
    __syncthreads();
    for (int wi = 0; wi < 47; wi++) {
      int w = half * 47 + wi;
      int jl = wi * 64 + lane;
      int j = j0 + jl;
      float jx1 = jb[0][jl], jy1 = jb[1][jl], jx2 = jb[2][jl], jy2 = jb[3][jl], ja = jb[4][jl];
      bool jv = j < K_SEL;
#pragma unroll
      for (int r = 0; r < 8; r++) {
        int i = ibase + r;
        float xl = fmaxf(ix1[r], jx1), yt = fmaxf(iy1[r], jy1);
        float xr = fminf(ix2[r], jx2), yb = fminf(iy2[r], jy2);
        float iw = fmaxf(xr - xl, 0.f), ihh = fmaxf(yb - yt, 0.f);
        float inter = iw * ihh;
        bool sup = jv && (j > i) && (inter > 0.7f * (ia[r] + ja - inter));
        u64 bits = __ballot(sup);
        if (lane == 0 && i < K_SEL) maskT[(size_t)w * SEL_PAD + i] = bits;
      }
    }
  }
}

// ---------------- 6. greedy NMS: multi-wave column pull (1 block x 16 waves) ----------------
__global__ __launch_bounds__(1024) void nms_k(const u64* __restrict__ maskT,
                                              const float* __restrict__ sx1, const float* __restrict__ sy1,
                                              const float* __restrict__ sx2, const float* __restrict__ sy2,
                                              u64* __restrict__ alive_out) {
  __shared__ u64 sdiag[94 * 64];
  __shared__ u64 skept[96];
  __shared__ u64 svalid[94];
  __shared__ u64 wacc[16];
  int tid = threadIdx.x;
  int wv = tid >> 6, lane = tid & 63;

  if (tid < 96) skept[tid] = 0ull;
  for (int w = wv; w < 94; w += 16) {
    int p = w * 64 + lane;
    float bw = sx2[p] - sx1[p], bh = sy2[p] - sy1[p];
    bool ok = (p < K_SEL) && (bw >= 16.f) && (bh >= 16.f);
    u64 bits = __ballot(ok);
    if (lane == 0) svalid[w] = bits;
  }
  for (int idx = tid; idx < 94 * 64; idx += 1024) {
    int cc = idx >> 6;
    sdiag[idx] = maskT[(size_t)cc * SEL_PAD + cc * 64 + (idx & 63)];
  }
  __syncthreads();

  for (int c = 0; c < 94; c++) {
    size_t colbase = (size_t)c * SEL_PAD;
    int i0 = 2 * tid;
    ulonglong2 v0 = *(const ulonglong2*)&maskT[colbase + i0];
    ulonglong2 v1 = *(const ulonglong2*)&maskT[colbase + i0 + 2048];
    ulonglong2 v2 = *(const ulonglong2*)&maskT[colbase + i0 + 4096];
    u64 k0 = skept[i0 >> 6];
    u64 k1 = skept[(i0 + 2048) >> 6];
    u64 k2 = skept[(i0 + 4096) >> 6];
    int sh = i0 & 63;
    u64 acc = 0;
    if ((k0 >> sh) & 1) acc |= v0.x;
    if ((k0 >> (sh + 1)) & 1) acc |= v0.y;
    if ((k1 >> sh) & 1) acc |= v1.x;
    if ((k1 >> (sh + 1)) & 1) acc |= v1.y;
    if ((k2 >> sh) & 1) acc |= v2.x;
    if ((k2 >> (sh + 1)) & 1) acc |= v2.y;
    u32 lo = (u32)acc, hi = (u32)(acc >> 32);
#pragma unroll
    for (int off = 1; off < 64; off <<= 1) {
      lo |= (u32)__shfl_xor((int)lo, off, 64);
      hi |= (u32)__shfl_xor((int)hi, off, 64);
    }
    if (lane == 0) wacc[wv] = ((u64)hi << 32) | (u64)lo;
    __syncthreads();
    if (wv == 0) {
      u64 a = wacc[lane & 15];
      u32 alo = (u32)a, ahi = (u32)(a >> 32);
#pragma unroll
      for (int off = 1; off < 16; off <<= 1) {
        alo |= (u32)__shfl_xor((int)alo, off, 64);
        ahi |= (u32)__shfl_xor((int)ahi, off, 64);
      }
      u64 supp = ((u64)ahi << 32) | (u64)alo;
      u64 cur = svalid[c] & ~supp;
      u64 d = sdiag[c * 64 + lane];
      u64 rem = cur, kept = 0;
      while (rem) {
        int b = __builtin_ctzll(rem);
        kept |= (1ull << b);
        u64 dead = shfl64(d, b);
        rem &= ~dead;
        rem &= ~(1ull << b);
      }
      if (lane == 0) skept[c] = kept;
    }
    __syncthreads();
  }
  if (tid < 94) alive_out[tid] = skept[tid];
}

// ---------------- 7. finalize ----------------
__global__ __launch_bounds__(128) void final_k(const u64* __restrict__ alive,
                                               const float* __restrict__ sx1, const float* __restrict__ sy1,
                                               const float* __restrict__ sx2, const float* __restrict__ sy2,
                                               const float* __restrict__ ssc, float* __restrict__ out) {
  __shared__ u64 aw[94];
  __shared__ u32 pre[95];
  int tid = threadIdx.x;
  if (tid < 94) aw[tid] = alive[tid];
  __syncthreads();
  if (tid == 0) {
    u32 s = 0;
    for (int w = 0; w < 94; w++) { pre[w] = s; s += (u32)__popcll(aw[w]); }
    pre[94] = s;
  }
  __syncthreads();
  u32 total = pre[94];
  for (int p = tid; p < K_SEL; p += 128) {
    int w = p >> 6, b = p & 63;
    u64 word = aw[w];
    u32 kb = pre[w] + (u32)__popcll(word & ((1ull << b) - 1ull));
    bool kept = (word >> b) & 1ull;
    int slot = -1; float sc = -1.f;
    if (kept) {
      if (kb < 300) { slot = (int)kb; sc = ssc[p]; }
    } else {
      u32 s2 = total + (u32)p - kb;
      if (s2 < 300) slot = (int)s2;
    }
    if (slot >= 0) {
      out[slot * 5 + 0] = sx1[p];
      out[slot * 5 + 1] = sy1[p];
      out[slot * 5 + 2] = sx2[p];
      out[slot * 5 + 3] = sy2[p];
      out[slot * 5 + 4] = sc;
    }
  }
}

extern "C" void kernel_launch(void* const* d_in, const int* in_sizes, int n_in,
                              void* d_out, int out_size, void* d_ws, size_t ws_size,
                              hipStream_t stream) {
  const float* feat   = (const float*)d_in[0];
  const float* conv_w = (const float*)d_in[2];
  const float* conv_b = (const float*)d_in[3];
  const float* cls_w  = (const float*)d_in[4];
  const float* cls_b  = (const float*)d_in[5];
  const float* bbox_w = (const float*)d_in[6];
  const float* bbox_b = (const float*)d_in[7];
  float* out = (float*)d_out;
  char* ws = (char*)d_ws;

  float*  rpn    = (float*)(ws + OFF_RPN);
  float4* boxes  = (float4*)(ws + OFF_BOXES);
  float*  scores = (float*)(ws + OFF_SCORES);
  u64*    keys   = (u64*)(ws + OFF_KEYS);
  SelState* st   = (SelState*)(ws + OFF_STATE);
  u64*    selk   = (u64*)(ws + OFF_SELK);
  float*  sx1    = (float*)(ws + OFF_SX1);
  float*  sy1    = (float*)(ws + OFF_SY1);
  float*  sx2    = (float*)(ws + OFF_SX2);
  float*  sy2    = (float*)(ws + OFF_SY2);
  float*  ssc    = (float*)(ws + OFF_SSC);
  u64*    alive  = (u64*)(ws + OFF_ALIVE);
  u64*    maskT  = (u64*)(ws + OFF_MASKT);

  conv_k<<<800, 256, 0, stream>>>(feat, conv_w, conv_b, rpn);
  heads_k<<<800, 256, 0, stream>>>(rpn, cls_w, cls_b, bbox_w, bbox_b, boxes, scores, keys);
  select_k<<<1, 1024, 0, stream>>>(keys, st);
  compact_k<<<900, 256, 0, stream>>>(keys, st, selk);
  rank_k<<<94, 64, 0, stream>>>(selk, boxes, scores, sx1, sy1, sx2, sy2, ssc);
  mask_k<<<188, 256, 0, stream>>>(sx1, sy1, sx2, sy2, maskT);
  nms_k<<<1, 1024, 0, stream>>>(maskT, sx1, sy1, sx2, sy2, alive);
  final_k<<<1, 128, 0, stream>>>(alive, sx1, sy1, sx2, sy2, ssc, out);
}

// Round 8
// 1666.689 us; speedup vs baseline: 1.0817x; 1.0817x over previous
//
#include <hip/hip_runtime.h>
#include <math.h>

typedef unsigned long long u64;
typedef unsigned int u32;

#define HH 160
#define WW 160
#define CC 256
#define NPX 25600
#define NA 9
#define NSC 230400
#define K_SEL 6000
#define SEL_PAD 6016
#define IMS 2560.0f
#define DWH 4.135166556742356f

struct SelState { u64 prefix; u32 r; u32 cnt; };

// ---- ws layout (bytes) ----
#define OFF_BOXES   0u               // float4[230400] -> 3,686,400
#define OFF_SCORES  3686400u         // float [230400]
#define OFF_KEYS    4608000u         // u64   [230400]
#define OFF_STATE   7499776u
#define OFF_SELK    7500032u         // u64[6016]
#define OFF_SX1     7548160u
#define OFF_SY1     7572224u
#define OFF_SX2     7596288u
#define OFF_SY2     7620352u
#define OFF_SSC     7644416u
#define OFF_ALIVE   7668480u
#define OFF_MASKT   11503104u        // u64[94*6016 + 128 pad] -> ends 16,028,160
#define OFF_RPN     27869184u        // float[256*160*160] -> ends 54,083,584

__constant__ float c_bx1[9] = {-91.f,-181.f,-362.f,-64.f,-128.f,-256.f,-45.f,-91.f,-181.f};
__constant__ float c_by1[9] = {-45.f,-91.f,-181.f,-64.f,-128.f,-256.f,-91.f,-181.f,-362.f};
__constant__ float c_bx2[9] = { 91.f, 181.f, 362.f, 64.f, 128.f, 256.f, 45.f, 91.f, 181.f};
__constant__ float c_by2[9] = { 45.f,  91.f, 181.f, 6.f+85.f, 128.f, 256.f, 91.f, 181.f, 362.f};
// NOTE: c_by2[3] must be 64: fixed below (91? no). Correct table re-declared:
__constant__ float c_by2f[9] = { 45.f, 91.f, 181.f, 64.f, 128.f, 256.f, 91.f, 181.f, 362.f};

__device__ inline u64 shfl64(u64 v, int src) {
  int lo = (int)(v & 0xFFFFFFFFull), hi = (int)(v >> 32);
  lo = __shfl(lo, src, 64); hi = __shfl(hi, src, 64);
  return ((u64)(u32)hi << 32) | (u32)lo;
}

// ---------------- 0. zero the conv accumulator buffer ----------------
__global__ __launch_bounds__(256) void zero_rpn_k(float4* __restrict__ p) {
  p[blockIdx.x * 256 + threadIdx.x] = make_float4(0.f, 0.f, 0.f, 0.f);
}

// ---------------- 1. conv3x3 partial sums (split-K2, implicit GEMM, fp32) ----------------
// grid 800 = 2 kh x 4 ot x 20 rt x 5 ct. Block: 64 oc x (8 rows x 32 cols), 128 ic.
// Thread: 8 oc x (2 rows x 4 cols) = 64 acc. icl loop NOT unrolled (I-cache).
// Output via fp32 atomicAdd (2 addends/elem, commutative => bit-stable).
#define ROW4(i, AV, r, B0, B1, B2, B3) \
  acc[i][r][0] += AV * B0; acc[i][r][1] += AV * B1; acc[i][r][2] += AV * B2; acc[i][r][3] += AV * B3;

#define TAPK(A0, A1, r, B0, B1, B2, B3) \
  ROW4(0, A0.x, r, B0, B1, B2, B3) ROW4(1, A0.y, r, B0, B1, B2, B3) \
  ROW4(2, A0.z, r, B0, B1, B2, B3) ROW4(3, A0.w, r, B0, B1, B2, B3) \
  ROW4(4, A1.x, r, B0, B1, B2, B3) ROW4(5, A1.y, r, B0, B1, B2, B3) \
  ROW4(6, A1.z, r, B0, B1, B2, B3) ROW4(7, A1.w, r, B0, B1, B2, B3)

#define DYTAPS(KB, QA, PA, QB, PB) \
  { const float* wr = &wsm[KB][0] + og8; \
    float4 a0 = *(const float4*)(wr); float4 a1 = *(const float4*)(wr + 4); \
    TAPK(a0, a1, 0, QA.x, QA.y, QA.z, QA.w) TAPK(a0, a1, 1, QB.x, QB.y, QB.z, QB.w) } \
  { const float* wr = &wsm[(KB) + 1][0] + og8; \
    float4 a0 = *(const float4*)(wr); float4 a1 = *(const float4*)(wr + 4); \
    TAPK(a0, a1, 0, QA.y, QA.z, QA.w, PA.x) TAPK(a0, a1, 1, QB.y, QB.z, QB.w, PB.x) } \
  { const float* wr = &wsm[(KB) + 2][0] + og8; \
    float4 a0 = *(const float4*)(wr); float4 a1 = *(const float4*)(wr + 4); \
    TAPK(a0, a1, 0, QA.z, QA.w, PA.x, PA.y) TAPK(a0, a1, 1, QB.z, QB.w, PB.x, PB.y) }

__global__ __launch_bounds__(256) void conv_k(const float* __restrict__ feat,
                                              const float* __restrict__ w,
                                              float* __restrict__ outp) {
  int bx = blockIdx.x;               // 800 = 2 * 4 * 20 * 5
  int ct = bx % 5;
  int rt = (bx / 5) % 20;
  int ot = (bx / 100) % 4;
  int kh = bx / 400;
  int x0 = ct * 32, y0 = rt * 8, oc0 = ot * 64, icb = kh * 128;

  __shared__ float wsm[72][68];      // [k=icl*9+tap][oc], 16B-aligned rows
  __shared__ float ps[8][10][36];    // [icl][row][col], 16B-aligned rows

  int tid = threadIdx.x;
  int og = tid >> 5;
  int og8 = og * 8;
  int pg = tid & 31;
  int rp = (pg >> 3) * 2;            // 0,2,4,6
  int col = (pg & 7) * 4;            // 0..28

  float acc[8][2][4];
#pragma unroll
  for (int i = 0; i < 8; i++)
#pragma unroll
    for (int r = 0; r < 2; r++)
#pragma unroll
      for (int j = 0; j < 4; j++) acc[i][r][j] = 0.f;

  for (int c8 = 0; c8 < 16; c8++) {
    int ic0 = icb + c8 * 8;
    __syncthreads();
    // weights: 64 oc x 72 k-values
    for (int idx = tid; idx < 4608; idx += 256) {
      int oc = idx / 72, j = idx % 72;
      wsm[j][oc] = w[(oc0 + oc) * 2304 + ic0 * 9 + j];
    }
    // pixels: 8 ic x 10 rows x 34 cols, zero-pad fused
    for (int it = 0; it < 11; it++) {
      int idx = tid + it * 256;
      if (idx < 2720) {
        int icl = idx / 340, rem = idx % 340;
        int r = rem / 34, c = rem % 34;
        int gy = y0 + r - 1, gx = x0 + c - 1;
        float v = 0.f;
        if ((unsigned)gy < 160u && (unsigned)gx < 160u)
          v = feat[(ic0 + icl) * NPX + gy * WW + gx];
        ps[icl][r][c] = v;
      }
    }
    __syncthreads();
    for (int icl = 0; icl < 8; icl++) {    // deliberately not unrolled
      const float* pb = &ps[icl][rp][col];
      float4 q0 = *(const float4*)pb;         float2 p0 = *(const float2*)(pb + 4);
      float4 q1 = *(const float4*)(pb + 36);  float2 p1 = *(const float2*)(pb + 40);
      float4 q2 = *(const float4*)(pb + 72);  float2 p2 = *(const float2*)(pb + 76);
      float4 q3 = *(const float4*)(pb + 108); float2 p3 = *(const float2*)(pb + 112);
      int kb = icl * 9;
      DYTAPS(kb,     q0, p0, q1, p1)
      DYTAPS(kb + 3, q1, p1, q2, p2)
      DYTAPS(kb + 6, q2, p2, q3, p3)
    }
  }
#pragma unroll
  for (int i = 0; i < 8; i++) {
    int oc = oc0 + og8 + i;
    float* obase = &outp[(size_t)oc * NPX + (y0 + rp) * WW + x0 + col];
#pragma unroll
    for (int r = 0; r < 2; r++)
#pragma unroll
      for (int j = 0; j < 4; j++)
        atomicAdd(obase + r * WW + j, acc[i][r][j]);
  }
}

// ---------------- 2. heads: bias+relu staging + 1x1 convs + decode + key ----------------
__global__ __launch_bounds__(256) void heads_k(const float* __restrict__ rpn,
                                               const float* __restrict__ conv_b,
                                               const float* __restrict__ cls_w,
                                               const float* __restrict__ cls_b,
                                               const float* __restrict__ bbox_w,
                                               const float* __restrict__ bbox_b,
                                               float4* __restrict__ boxes,
                                               float* __restrict__ scores,
                                               u64* __restrict__ keys) {
  __shared__ float sf[32][260];
  __shared__ float so[45][33];
  int tid = threadIdx.x;
  int px0 = blockIdx.x * 32;
  for (int idx = tid; idx < 8192; idx += 256) {
    int c = idx >> 5, p = idx & 31;
    sf[p][c] = fmaxf(rpn[(size_t)c * NPX + px0 + p] + conv_b[c], 0.f);
  }
  __syncthreads();
  int p = tid & 31, g = tid >> 5;
  for (int oi = 0; oi < 6; oi++) {
    int o = g + oi * 8;
    if (o >= 45) break;
    const float* wr = (o < 9) ? (cls_w + o * CC) : (bbox_w + (o - 9) * CC);
    float bsum = (o < 9) ? cls_b[o] : bbox_b[o - 9];
    float s = 0.f;
    for (int c = 0; c < CC; c += 4) {
      float4 f = *(const float4*)&sf[p][c];
      float4 wv = *(const float4*)&wr[c];
      s += f.x * wv.x; s += f.y * wv.y; s += f.z * wv.z; s += f.w * wv.w;
    }
    so[o][p] = s + bsum;
  }
  __syncthreads();
  for (int t = tid; t < 288; t += 256) {
    int a = t >> 5, pp = t & 31;
    int px = px0 + pp;
    int y = px / 160, x = px - y * 160;
    float logit = so[a][pp];
    float sc = 1.f / (1.f + expf(-logit));
    float ddx = so[9 + 4 * a][pp], ddy = so[10 + 4 * a][pp];
    float ddw = fminf(so[11 + 4 * a][pp], DWH);
    float ddh = fminf(so[12 + 4 * a][pp], DWH);
    float ax1 = x * 16.f + c_bx1[a];
    float ay1 = y * 16.f + c_by1[a];
    float ax2 = x * 16.f + c_bx2[a];
    float ay2 = y * 16.f + c_by2f[a];
    float aw = ax2 - ax1, ah = ay2 - ay1;
    float cx = ax1 + 0.5f * aw, cy = ay1 + 0.5f * ah;
    float pcx = ddx * aw + cx, pcy = ddy * ah + cy;
    float pw = expf(ddw) * aw, phh = expf(ddh) * ah;
    float x1 = pcx - 0.5f * pw, y1 = pcy - 0.5f * phh;
    float x2 = pcx + 0.5f * pw, y2 = pcy + 0.5f * phh;
    x1 = fminf(fmaxf(x1, 0.f), IMS); x2 = fminf(fmaxf(x2, 0.f), IMS);
    y1 = fminf(fmaxf(y1, 0.f), IMS); y2 = fminf(fmaxf(y2, 0.f), IMS);
    int gidx = px * 9 + a;
    boxes[gidx] = make_float4(x1, y1, x2, y2);
    scores[gidx] = sc;
    u32 sb = __float_as_uint(sc);
    u32 mono = (sb & 0x80000000u) ? ~sb : (sb | 0x80000000u);
    keys[gidx] = ((u64)mono << 32) | (u64)(0xFFFFFFFFu - (u32)gidx);
  }
}

// ---------------- 3. single-block radix select (R6 version, reverted) ----------------
__global__ __launch_bounds__(1024) void select_k(const u64* __restrict__ keys, SelState* st) {
  __shared__ u32 hist[8192];
  __shared__ u32 tsum[1024];
  __shared__ u32 wsum[16];
  __shared__ u64 sprefix;
  __shared__ u32 sr;
  int tid = threadIdx.x;
  int lane = tid & 63, wv = tid >> 6;
  u64 prefix = 0;
  u32 r = K_SEL;
  int bitsdone = 0;
  const int widths[5] = {13, 13, 13, 13, 12};

  for (int pass = 0; pass < 5; pass++) {
    int wbits = widths[pass];
    int nbins = 1 << wbits;
    int shift = 64 - bitsdone - wbits;
    for (int i = tid; i < nbins; i += 1024) hist[i] = 0;
    __syncthreads();

#define PROC(kk)                                                            \
    {                                                                       \
      bool active = (bitsdone == 0) || (((kk) >> (64 - bitsdone)) == prefix); \
      u32 digit = (u32)(((kk) >> shift) & (u64)(nbins - 1));                \
      u64 act = __ballot(active);                                           \
      bool done = false;                                                    \
      if (act == ~0ull) {                                                   \
        u32 d0 = (u32)__shfl((int)digit, 0, 64);                            \
        if (__ballot(digit == d0) == ~0ull) {                               \
          if (lane == 0) atomicAdd(&hist[d0], 64u);                         \
          done = true;                                                      \
        }                                                                   \
      }                                                                     \
      if (!done && active) atomicAdd(&hist[digit], 1u);                     \
    }

    int i = tid;
    for (int it = 0; it < 56; it++, i += 4096) {
      u64 k0 = keys[i];
      u64 k1 = keys[i + 1024];
      u64 k2 = keys[i + 2048];
      u64 k3 = keys[i + 3072];
      PROC(k0) PROC(k1) PROC(k2) PROC(k3)
    }
    { u64 k4 = keys[i]; PROC(k4) }   // covers 230400
#undef PROC
    __syncthreads();

    int bpt = nbins >> 10;
    u32 s = 0;
    for (int b = 0; b < bpt; b++) s += hist[tid * bpt + b];
    tsum[tid] = s;
    u32 v = s;
#pragma unroll
    for (int off = 1; off < 64; off <<= 1) v += (u32)__shfl_xor((int)v, off, 64);
    if (lane == 0) wsum[wv] = v;
    __syncthreads();

    if (tid == 0) {
      u32 cum = 0;
      int ws = 15;
      while (ws > 0 && cum + wsum[ws] < r) { cum += wsum[ws]; ws--; }
      int t = ws * 64 + 63, tend = ws * 64;
      while (t > tend && cum + tsum[t] < r) { cum += tsum[t]; t--; }
      int b = t * bpt + bpt - 1, bend = t * bpt;
      while (b > bend && cum + hist[b] < r) { cum += hist[b]; b--; }
      sprefix = (prefix << wbits) | (u64)(u32)b;
      sr = r - cum;
    }
    __syncthreads();
    prefix = sprefix;
    r = sr;
    bitsdone += wbits;
    __syncthreads();
  }
  if (tid == 0) {
    st->prefix = prefix;
    st->r = r;
    st->cnt = 0;
  }
}

__global__ __launch_bounds__(256) void compact_k(const u64* __restrict__ keys,
                                                 SelState* st, u64* __restrict__ selk) {
  int idx = blockIdx.x * 256 + threadIdx.x;
  u64 k = keys[idx];
  if (k >= st->prefix) {
    u32 pos = atomicAdd(&st->cnt, 1u);
    selk[pos] = k;
  }
}

// ---------------- 4. exact rank -> sorted SoA ----------------
__global__ __launch_bounds__(64) void rank_k(const u64* __restrict__ selk,
                                             const float4* __restrict__ boxes,
                                             const float* __restrict__ scores,
                                             float* sx1, float* sy1, float* sx2, float* sy2, float* ssc) {
  __shared__ __align__(16) u64 sk[SEL_PAD];
  int lane = threadIdx.x;
  for (int i = lane; i < SEL_PAD; i += 64) sk[i] = (i < K_SEL) ? selk[i] : 0ull;
  __syncthreads();
  int n = blockIdx.x * 64 + lane;
  u64 myk = (n < K_SEL) ? selk[n] : ~0ull;
  int cnt = 0;
  const ulonglong2* sk2 = (const ulonglong2*)sk;
  for (int j = 0; j < SEL_PAD / 2; j++) {
    ulonglong2 kk = sk2[j];
    cnt += (kk.x > myk) ? 1 : 0;
    cnt += (kk.y > myk) ? 1 : 0;
  }
  if (n < K_SEL) {
    u32 oidx = 0xFFFFFFFFu - (u32)(myk & 0xFFFFFFFFull);
    float4 b = boxes[oidx];
    sx1[cnt] = b.x; sy1[cnt] = b.y; sx2[cnt] = b.z; sy2[cnt] = b.w;
    ssc[cnt] = scores[oidx];
  }
}

// ---------------- 5. pairwise suppression mask (column-major) ----------------
__global__ __launch_bounds__(256) void mask_k(const float* __restrict__ sx1, const float* __restrict__ sy1,
                                              const float* __restrict__ sx2, const float* __restrict__ sy2,
                                              u64* __restrict__ maskT) {
  __shared__ float jb[5][3008];
  int tid = threadIdx.x;
  int wv = tid >> 6, lane = tid & 63;
  int ibase = blockIdx.x * 32 + wv * 8;
  float ix1[8], iy1[8], ix2[8], iy2[8], ia[8];
#pragma unroll
  for (int r = 0; r < 8; r++) {
    int i = ibase + r;
    ix1[r] = sx1[i]; iy1[r] = sy1[i]; ix2[r] = sx2[i]; iy2[r] = sy2[i];
    ia[r] = (ix2[r] - ix1[r]) * (iy2[r] - iy1[r]);
  }
  for (int half = 0; half < 2; half++) {
    int j0 = half * 3008;
    __syncthreads();
    for (int idx = tid; idx < 3008; idx += 256) {
      int j = j0 + idx;
      bool v = j < K_SEL;
      float a = v ? sx1[j] : 0.f;
      float b = v ? sy1[j] : 0.f;
      float c = v ? sx2[j] : 0.f;
      float d = v ? sy2[j] : 0.f;
      jb[0][idx] = a; jb[1][idx] = b; jb[2][idx] = c; jb[3][idx] = d;
      jb[4][idx] = (c - a) * (d - b);
    }
    __syncthreads();
    for (int wi = 0; wi < 47; wi++) {
      int w = half * 47 + wi;
      int jl = wi * 64 + lane;
      int j = j0 + jl;
      float jx1 = jb[0][jl], jy1 = jb[1][jl], jx2 = jb[2][jl], jy2 = jb[3][jl], ja = jb[4][jl];
      bool jv = j < K_SEL;
#pragma unroll
      for (int r = 0; r < 8; r++) {
        int i = ibase + r;
        float xl = fmaxf(ix1[r], jx1), yt = fmaxf(iy1[r], jy1);
        float xr = fminf(ix2[r], jx2), yb = fminf(iy2[r], jy2);
        float iw = fmaxf(xr - xl, 0.f), ihh = fmaxf(yb - yt, 0.f);
        float inter = iw * ihh;
        bool sup = jv && (j > i) && (inter > 0.7f * (ia[r] + ja - inter));
        u64 bits = __ballot(sup);
        if (lane == 0 && i < K_SEL) maskT[(size_t)w * SEL_PAD + i] = bits;
      }
    }
  }
}

// ---------------- 6. greedy NMS: multi-wave column pull (1 block x 16 waves) ----------------
__global__ __launch_bounds__(1024) void nms_k(const u64* __restrict__ maskT,
                                              const float* __restrict__ sx1, const float* __restrict__ sy1,
                                              const float* __restrict__ sx2, const float* __restrict__ sy2,
                                              u64* __restrict__ alive_out) {
  __shared__ u64 sdiag[94 * 64];
  __shared__ u64 skept[96];
  __shared__ u64 svalid[94];
  __shared__ u64 wacc[16];
  int tid = threadIdx.x;
  int wv = tid >> 6, lane = tid & 63;

  if (tid < 96) skept[tid] = 0ull;
  for (int w = wv; w < 94; w += 16) {
    int p = w * 64 + lane;
    float bw = sx2[p] - sx1[p], bh = sy2[p] - sy1[p];
    bool ok = (p < K_SEL) && (bw >= 16.f) && (bh >= 16.f);
    u64 bits = __ballot(ok);
    if (lane == 0) svalid[w] = bits;
  }
  for (int idx = tid; idx < 94 * 64; idx += 1024) {
    int cc = idx >> 6;
    sdiag[idx] = maskT[(size_t)cc * SEL_PAD + cc * 64 + (idx & 63)];
  }
  __syncthreads();

  for (int c = 0; c < 94; c++) {
    size_t colbase = (size_t)c * SEL_PAD;
    int i0 = 2 * tid;
    ulonglong2 v0 = *(const ulonglong2*)&maskT[colbase + i0];
    ulonglong2 v1 = *(const ulonglong2*)&maskT[colbase + i0 + 2048];
    ulonglong2 v2 = *(const ulonglong2*)&maskT[colbase + i0 + 4096];
    u64 k0 = skept[i0 >> 6];
    u64 k1 = skept[(i0 + 2048) >> 6];
    u64 k2 = skept[(i0 + 4096) >> 6];
    int sh = i0 & 63;
    u64 acc = 0;
    if ((k0 >> sh) & 1) acc |= v0.x;
    if ((k0 >> (sh + 1)) & 1) acc |= v0.y;
    if ((k1 >> sh) & 1) acc |= v1.x;
    if ((k1 >> (sh + 1)) & 1) acc |= v1.y;
    if ((k2 >> sh) & 1) acc |= v2.x;
    if ((k2 >> (sh + 1)) & 1) acc |= v2.y;
    u32 lo = (u32)acc, hi = (u32)(acc >> 32);
#pragma unroll
    for (int off = 1; off < 64; off <<= 1) {
      lo |= (u32)__shfl_xor((int)lo, off, 64);
      hi |= (u32)__shfl_xor((int)hi, off, 64);
    }
    if (lane == 0) wacc[wv] = ((u64)hi << 32) | (u64)lo;
    __syncthreads();
    if (wv == 0) {
      u64 a = wacc[lane & 15];
      u32 alo = (u32)a, ahi = (u32)(a >> 32);
#pragma unroll
      for (int off = 1; off < 16; off <<= 1) {
        alo |= (u32)__shfl_xor((int)alo, off, 64);
        ahi |= (u32)__shfl_xor((int)ahi, off, 64);
      }
      u64 supp = ((u64)ahi << 32) | (u64)alo;
      u64 cur = svalid[c] & ~supp;
      u64 d = sdiag[c * 64 + lane];
      u64 rem = cur, kept = 0;
      while (rem) {
        int b = __builtin_ctzll(rem);
        kept |= (1ull << b);
        u64 dead = shfl64(d, b);
        rem &= ~dead;
        rem &= ~(1ull << b);
      }
      if (lane == 0) skept[c] = kept;
    }
    __syncthreads();
  }
  if (tid < 94) alive_out[tid] = skept[tid];
}

// ---------------- 7. finalize ----------------
__global__ __launch_bounds__(128) void final_k(const u64* __restrict__ alive,
                                               const float* __restrict__ sx1, const float* __restrict__ sy1,
                                               const float* __restrict__ sx2, const float* __restrict__ sy2,
                                               const float* __restrict__ ssc, float* __restrict__ out) {
  __shared__ u64 aw[94];
  __shared__ u32 pre[95];
  int tid = threadIdx.x;
  if (tid < 94) aw[tid] = alive[tid];
  __syncthreads();
  if (tid == 0) {
    u32 s = 0;
    for (int w = 0; w < 94; w++) { pre[w] = s; s += (u32)__popcll(aw[w]); }
    pre[94] = s;
  }
  __syncthreads();
  u32 total = pre[94];
  for (int p = tid; p < K_SEL; p += 128) {
    int w = p >> 6, b = p & 63;
    u64 word = aw[w];
    u32 kb = pre[w] + (u32)__popcll(word & ((1ull << b) - 1ull));
    bool kept = (word >> b) & 1ull;
    int slot = -1; float sc = -1.f;
    if (kept) {
      if (kb < 300) { slot = (int)kb; sc = ssc[p]; }
    } else {
      u32 s2 = total + (u32)p - kb;
      if (s2 < 300) slot = (int)s2;
    }
    if (slot >= 0) {
      out[slot * 5 + 0] = sx1[p];
      out[slot * 5 + 1] = sy1[p];
      out[slot * 5 + 2] = sx2[p];
      out[slot * 5 + 3] = sy2[p];
      out[slot * 5 + 4] = sc;
    }
  }
}

extern "C" void kernel_launch(void* const* d_in, const int* in_sizes, int n_in,
                              void* d_out, int out_size, void* d_ws, size_t ws_size,
                              hipStream_t stream) {
  const float* feat   = (const float*)d_in[0];
  const float* conv_w = (const float*)d_in[2];
  const float* conv_b = (const float*)d_in[3];
  const float* cls_w  = (const float*)d_in[4];
  const float* cls_b  = (const float*)d_in[5];
  const float* bbox_w = (const float*)d_in[6];
  const float* bbox_b = (const float*)d_in[7];
  float* out = (float*)d_out;
  char* ws = (char*)d_ws;

  float*  rpn    = (float*)(ws + OFF_RPN);
  float4* boxes  = (float4*)(ws + OFF_BOXES);
  float*  scores = (float*)(ws + OFF_SCORES);
  u64*    keys   = (u64*)(ws + OFF_KEYS);
  SelState* st   = (SelState*)(ws + OFF_STATE);
  u64*    selk   = (u64*)(ws + OFF_SELK);
  float*  sx1    = (float*)(ws + OFF_SX1);
  float*  sy1    = (float*)(ws + OFF_SY1);
  float*  sx2    = (float*)(ws + OFF_SX2);
  float*  sy2    = (float*)(ws + OFF_SY2);
  float*  ssc    = (float*)(ws + OFF_SSC);
  u64*    alive  = (u64*)(ws + OFF_ALIVE);
  u64*    maskT  = (u64*)(ws + OFF_MASKT);

  zero_rpn_k<<<6400, 256, 0, stream>>>((float4*)rpn);
  conv_k<<<800, 256, 0, stream>>>(feat, conv_w, rpn);
  heads_k<<<800, 256, 0, stream>>>(rpn, conv_b, cls_w, cls_b, bbox_w, bbox_b, boxes, scores, keys);
  select_k<<<1, 1024, 0, stream>>>(keys, st);
  compact_k<<<900, 256, 0, stream>>>(keys, st, selk);
  rank_k<<<94, 64, 0, stream>>>(selk, boxes, scores, sx1, sy1, sx2, sy2, ssc);
  mask_k<<<188, 256, 0, stream>>>(sx1, sy1, sx2, sy2, maskT);
  nms_k<<<1, 1024, 0, stream>>>(maskT, sx1, sy1, sx2, sy2, alive);
  final_k<<<1, 128, 0, stream>>>(alive, sx1, sy1, sx2, sy2, ssc, out);
}

// Round 9
// 1562.041 us; speedup vs baseline: 1.1542x; 1.0670x over previous
//
#include <hip/hip_runtime.h>
#include <math.h>

typedef unsigned long long u64;
typedef unsigned int u32;

#define HH 160
#define WW 160
#define CC 256
#define NPX 25600
#define NA 9
#define NSC 230400
#define K_SEL 6000
#define SEL_PAD 6016
#define IMS 2560.0f
#define DWH 4.135166556742356f

struct SelState { u64 prefix; u32 r; u32 cnt; };

// ---- ws layout (bytes) ----
#define OFF_BOXES   0u               // float4[230400] -> 3,686,400
#define OFF_SCORES  3686400u         // float [230400]
#define OFF_KEYS    4608000u         // u64   [230400]
#define OFF_STATE   7499776u
#define OFF_SELK    7500032u         // u64[6016]
#define OFF_SX1     7548160u
#define OFF_SY1     7572224u
#define OFF_SX2     7596288u
#define OFF_SY2     7620352u
#define OFF_SSC     7644416u
#define OFF_ALIVE   7668480u
#define OFF_MASKT   11503104u        // u64[94*6016 + 128 pad] -> ends 16,028,160
#define OFF_WT      16028160u        // float[2304*256] -> ends 18,387,456
#define OFF_RPN     27869184u        // float[256*160*160] -> ends 54,083,584

__constant__ float c_bx1[9] = {-91.f,-181.f,-362.f,-64.f,-128.f,-256.f,-45.f,-91.f,-181.f};
__constant__ float c_by1[9] = {-45.f,-91.f,-181.f,-64.f,-128.f,-256.f,-91.f,-181.f,-362.f};
__constant__ float c_bx2[9] = { 91.f, 181.f, 362.f, 64.f, 128.f, 256.f, 45.f, 91.f, 181.f};
__constant__ float c_by2[9] = { 45.f,  91.f, 181.f, 64.f, 128.f, 256.f, 91.f, 181.f, 362.f};

__device__ inline u64 shfl64(u64 v, int src) {
  int lo = (int)(v & 0xFFFFFFFFull), hi = (int)(v >> 32);
  lo = __shfl(lo, src, 64); hi = __shfl(hi, src, 64);
  return ((u64)(u32)hi << 32) | (u32)lo;
}

// ---------------- 0. weight transpose: w[oc][ic*9+tap] -> wT[ic*9+tap][oc] ----------------
// 64x64 LDS tiles, coalesced reads AND writes. grid 144 = 36 ktiles x 4 octiles.
__global__ __launch_bounds__(256) void wtr_k(const float* __restrict__ w, float* __restrict__ wT) {
  __shared__ float t[64][65];
  int kb = blockIdx.x % 36;
  int ob = blockIdx.x / 36;
  int tid = threadIdx.x;
  for (int it = 0; it < 16; it++) {
    int idx = it * 256 + tid;
    int row = idx >> 6, colk = idx & 63;        // row = oc-local, colk = k-local
    t[row][colk] = w[(size_t)(ob * 64 + row) * 2304 + kb * 64 + colk];
  }
  __syncthreads();
  for (int it = 0; it < 16; it++) {
    int idx = it * 256 + tid;
    int krow = idx >> 6, occ = idx & 63;
    wT[(size_t)(kb * 64 + krow) * 256 + ob * 64 + occ] = t[occ][krow];
  }
}

// ---------------- 1. conv3x3 + bias + relu (scalar-weight implicit GEMM, fp32) ----------------
// grid 800 = 5 ct x 40 rt x 4 ot. Block: 4 waves; each wave owns a UNIFORM 16-oc
// slice (readfirstlane -> weights via s_load, SGPR operand of v_fmac) x 128 px
// (4 rows x 32 cols). Thread: 2 px rows x 16 oc = 32 acc. Pixels via 12
// consecutive-address ds_read_b32 per icl feeding 288 FMAs.
__global__ __launch_bounds__(256) void conv_k(const float* __restrict__ feat,
                                              const float* __restrict__ wT,
                                              const float* __restrict__ bias,
                                              float* __restrict__ outp) {
  int bx = blockIdx.x;              // 800 = 5 * 40 * 4
  int ct = bx % 5;
  int rt = (bx / 5) % 40;
  int ot = bx / 200;
  int x0 = ct * 32, y0 = rt * 4, oc0 = ot * 64;

  __shared__ float ps[8][6][36];    // [icl][row y0-1..y0+4][col x0-1..x0+32]

  int tid = threadIdx.x;
  int lane = tid & 63;
  int wvu = __builtin_amdgcn_readfirstlane(tid >> 6);   // wave id 0..3, SGPR-uniform
  int col = lane & 31;
  int s = lane >> 5;                // row-slot: thread covers rows y0+2s, y0+2s+1
  int ocw = oc0 + wvu * 16;         // uniform; 64B-aligned for s_load_dwordx16

  float acc0[16], acc1[16];
#pragma unroll
  for (int i = 0; i < 16; i++) { acc0[i] = 0.f; acc1[i] = 0.f; }

  for (int c8 = 0; c8 < 32; c8++) {
    int ic0 = c8 * 8;
    __syncthreads();
    for (int it = 0; it < 7; it++) {
      int idx = tid + it * 256;
      if (idx < 1632) {
        int icl = idx / 204, rem = idx % 204;
        int r = rem / 34, c = rem % 34;
        int gy = y0 + r - 1, gx = x0 + c - 1;
        float v = 0.f;
        if ((unsigned)gy < 160u && (unsigned)gx < 160u)
          v = feat[(ic0 + icl) * NPX + gy * WW + gx];
        ps[icl][r][c] = v;
      }
    }
    __syncthreads();
    for (int icl = 0; icl < 8; icl++) {       // not unrolled: keep I-cache happy
      float p[4][3];
#pragma unroll
      for (int rr = 0; rr < 4; rr++)
#pragma unroll
        for (int cc = 0; cc < 3; cc++)
          p[rr][cc] = ps[icl][2 * s + rr][col + cc];
      const float* wb = wT + (size_t)(ic0 + icl) * 9 * 256 + ocw;   // uniform addr
#pragma unroll
      for (int dy = 0; dy < 3; dy++) {
#pragma unroll
        for (int dx = 0; dx < 3; dx++) {
          const float* wr = wb + (dy * 3 + dx) * 256;
#pragma unroll
          for (int i = 0; i < 16; i++) {
            float wv_ = wr[i];                // s_load -> SGPR operand
            acc0[i] += wv_ * p[dy][dx];
            acc1[i] += wv_ * p[dy + 1][dx];
          }
        }
      }
    }
  }
#pragma unroll
  for (int i = 0; i < 16; i++) {
    int oc = ocw + i;
    float bv = bias[oc];
    size_t base = (size_t)oc * NPX + (y0 + 2 * s) * WW + x0 + col;
    outp[base] = fmaxf(acc0[i] + bv, 0.f);
    outp[base + WW] = fmaxf(acc1[i] + bv, 0.f);
  }
}

// ---------------- 2. heads + sigmoid + decode + clip + key ----------------
__global__ __launch_bounds__(256) void heads_k(const float* __restrict__ rpn,
                                               const float* __restrict__ cls_w,
                                               const float* __restrict__ cls_b,
                                               const float* __restrict__ bbox_w,
                                               const float* __restrict__ bbox_b,
                                               float4* __restrict__ boxes,
                                               float* __restrict__ scores,
                                               u64* __restrict__ keys) {
  __shared__ float sf[32][260];
  __shared__ float so[45][33];
  int tid = threadIdx.x;
  int px0 = blockIdx.x * 32;
  for (int idx = tid; idx < 8192; idx += 256) {
    int c = idx >> 5, p = idx & 31;
    sf[p][c] = rpn[(size_t)c * NPX + px0 + p];
  }
  __syncthreads();
  int p = tid & 31, g = tid >> 5;
  for (int oi = 0; oi < 6; oi++) {
    int o = g + oi * 8;
    if (o >= 45) break;
    const float* wr = (o < 9) ? (cls_w + o * CC) : (bbox_w + (o - 9) * CC);
    float bsum = (o < 9) ? cls_b[o] : bbox_b[o - 9];
    float s = 0.f;
    for (int c = 0; c < CC; c += 4) {
      float4 f = *(const float4*)&sf[p][c];
      float4 wv = *(const float4*)&wr[c];
      s += f.x * wv.x; s += f.y * wv.y; s += f.z * wv.z; s += f.w * wv.w;
    }
    so[o][p] = s + bsum;
  }
  __syncthreads();
  for (int t = tid; t < 288; t += 256) {
    int a = t >> 5, pp = t & 31;
    int px = px0 + pp;
    int y = px / 160, x = px - y * 160;
    float logit = so[a][pp];
    float sc = 1.f / (1.f + expf(-logit));
    float ddx = so[9 + 4 * a][pp], ddy = so[10 + 4 * a][pp];
    float ddw = fminf(so[11 + 4 * a][pp], DWH);
    float ddh = fminf(so[12 + 4 * a][pp], DWH);
    float ax1 = x * 16.f + c_bx1[a];
    float ay1 = y * 16.f + c_by1[a];
    float ax2 = x * 16.f + c_bx2[a];
    float ay2 = y * 16.f + c_by2[a];
    float aw = ax2 - ax1, ah = ay2 - ay1;
    float cx = ax1 + 0.5f * aw, cy = ay1 + 0.5f * ah;
    float pcx = ddx * aw + cx, pcy = ddy * ah + cy;
    float pw = expf(ddw) * aw, phh = expf(ddh) * ah;
    float x1 = pcx - 0.5f * pw, y1 = pcy - 0.5f * phh;
    float x2 = pcx + 0.5f * pw, y2 = pcy + 0.5f * phh;
    x1 = fminf(fmaxf(x1, 0.f), IMS); x2 = fminf(fmaxf(x2, 0.f), IMS);
    y1 = fminf(fmaxf(y1, 0.f), IMS); y2 = fminf(fmaxf(y2, 0.f), IMS);
    int gidx = px * 9 + a;
    boxes[gidx] = make_float4(x1, y1, x2, y2);
    scores[gidx] = sc;
    u32 sb = __float_as_uint(sc);
    u32 mono = (sb & 0x80000000u) ? ~sb : (sb | 0x80000000u);
    keys[gidx] = ((u64)mono << 32) | (u64)(0xFFFFFFFFu - (u32)gidx);
  }
}

// ---------------- 3. single-block radix select ----------------
__global__ __launch_bounds__(1024) void select_k(const u64* __restrict__ keys, SelState* st) {
  __shared__ u32 hist[8192];
  __shared__ u32 tsum[1024];
  __shared__ u32 wsum[16];
  __shared__ u64 sprefix;
  __shared__ u32 sr;
  int tid = threadIdx.x;
  int lane = tid & 63, wv = tid >> 6;
  u64 prefix = 0;
  u32 r = K_SEL;
  int bitsdone = 0;
  const int widths[5] = {13, 13, 13, 13, 12};

  for (int pass = 0; pass < 5; pass++) {
    int wbits = widths[pass];
    int nbins = 1 << wbits;
    int shift = 64 - bitsdone - wbits;
    for (int i = tid; i < nbins; i += 1024) hist[i] = 0;
    __syncthreads();

#define PROC(kk)                                                            \
    {                                                                       \
      bool active = (bitsdone == 0) || (((kk) >> (64 - bitsdone)) == prefix); \
      u32 digit = (u32)(((kk) >> shift) & (u64)(nbins - 1));                \
      u64 act = __ballot(active);                                           \
      bool done = false;                                                    \
      if (act == ~0ull) {                                                   \
        u32 d0 = (u32)__shfl((int)digit, 0, 64);                            \
        if (__ballot(digit == d0) == ~0ull) {                               \
          if (lane == 0) atomicAdd(&hist[d0], 64u);                         \
          done = true;                                                      \
        }                                                                   \
      }                                                                     \
      if (!done && active) atomicAdd(&hist[digit], 1u);                     \
    }

    int i = tid;
    for (int it = 0; it < 56; it++, i += 4096) {
      u64 k0 = keys[i];
      u64 k1 = keys[i + 1024];
      u64 k2 = keys[i + 2048];
      u64 k3 = keys[i + 3072];
      PROC(k0) PROC(k1) PROC(k2) PROC(k3)
    }
    { u64 k4 = keys[i]; PROC(k4) }   // covers 230400
#undef PROC
    __syncthreads();

    int bpt = nbins >> 10;
    u32 s = 0;
    for (int b = 0; b < bpt; b++) s += hist[tid * bpt + b];
    tsum[tid] = s;
    u32 v = s;
#pragma unroll
    for (int off = 1; off < 64; off <<= 1) v += (u32)__shfl_xor((int)v, off, 64);
    if (lane == 0) wsum[wv] = v;
    __syncthreads();

    if (tid == 0) {
      u32 cum = 0;
      int ws = 15;
      while (ws > 0 && cum + wsum[ws] < r) { cum += wsum[ws]; ws--; }
      int t = ws * 64 + 63, tend = ws * 64;
      while (t > tend && cum + tsum[t] < r) { cum += tsum[t]; t--; }
      int b = t * bpt + bpt - 1, bend = t * bpt;
      while (b > bend && cum + hist[b] < r) { cum += hist[b]; b--; }
      sprefix = (prefix << wbits) | (u64)(u32)b;
      sr = r - cum;
    }
    __syncthreads();
    prefix = sprefix;
    r = sr;
    bitsdone += wbits;
    __syncthreads();
  }
  if (tid == 0) {
    st->prefix = prefix;
    st->r = r;
    st->cnt = 0;
  }
}

__global__ __launch_bounds__(256) void compact_k(const u64* __restrict__ keys,
                                                 SelState* st, u64* __restrict__ selk) {
  int idx = blockIdx.x * 256 + threadIdx.x;
  u64 k = keys[idx];
  if (k >= st->prefix) {
    u32 pos = atomicAdd(&st->cnt, 1u);
    selk[pos] = k;
  }
}

// ---------------- 4. exact rank -> sorted SoA ----------------
__global__ __launch_bounds__(64) void rank_k(const u64* __restrict__ selk,
                                             const float4* __restrict__ boxes,
                                             const float* __restrict__ scores,
                                             float* sx1, float* sy1, float* sx2, float* sy2, float* ssc) {
  __shared__ __align__(16) u64 sk[SEL_PAD];
  int lane = threadIdx.x;
  for (int i = lane; i < SEL_PAD; i += 64) sk[i] = (i < K_SEL) ? selk[i] : 0ull;
  __syncthreads();
  int n = blockIdx.x * 64 + lane;
  u64 myk = (n < K_SEL) ? selk[n] : ~0ull;
  int cnt = 0;
  const ulonglong2* sk2 = (const ulonglong2*)sk;
  for (int j = 0; j < SEL_PAD / 2; j++) {
    ulonglong2 kk = sk2[j];
    cnt += (kk.x > myk) ? 1 : 0;
    cnt += (kk.y > myk) ? 1 : 0;
  }
  if (n < K_SEL) {
    u32 oidx = 0xFFFFFFFFu - (u32)(myk & 0xFFFFFFFFull);
    float4 b = boxes[oidx];
    sx1[cnt] = b.x; sy1[cnt] = b.y; sx2[cnt] = b.z; sy2[cnt] = b.w;
    ssc[cnt] = scores[oidx];
  }
}

// ---------------- 5. pairwise suppression mask (column-major) ----------------
__global__ __launch_bounds__(256) void mask_k(const float* __restrict__ sx1, const float* __restrict__ sy1,
                                              const float* __restrict__ sx2, const float* __restrict__ sy2,
                                              u64* __restrict__ maskT) {
  __shared__ float jb[5][3008];
  int tid = threadIdx.x;
  int wv = tid >> 6, lane = tid & 63;
  int ibase = blockIdx.x * 32 + wv * 8;
  float ix1[8], iy1[8], ix2[8], iy2[8], ia[8];
#pragma unroll
  for (int r = 0; r < 8; r++) {
    int i = ibase + r;
    ix1[r] = sx1[i]; iy1[r] = sy1[i]; ix2[r] = sx2[i]; iy2[r] = sy2[i];
    ia[r] = (ix2[r] - ix1[r]) * (iy2[r] - iy1[r]);
  }
  for (int half = 0; half < 2; half++) {
    int j0 = half * 3008;
    __syncthreads();
    for (int idx = tid; idx < 3008; idx += 256) {
      int j = j0 + idx;
      bool v = j < K_SEL;
      float a = v ? sx1[j] : 0.f;
      float b = v ? sy1[j] : 0.f;
      float c = v ? sx2[j] : 0.f;
      float d = v ? sy2[j] : 0.f;
      jb[0][idx] = a; jb[1][idx] = b; jb[2][idx] = c; jb[3][idx] = d;
      jb[4][idx] = (c - a) * (d - b);
    }
    __syncthreads();
    for (int wi = 0; wi < 47; wi++) {
      int w = half * 47 + wi;
      int jl = wi * 64 + lane;
      int j = j0 + jl;
      float jx1 = jb[0][jl], jy1 = jb[1][jl], jx2 = jb[2][jl], jy2 = jb[3][jl], ja = jb[4][jl];
      bool jv = j < K_SEL;
#pragma unroll
      for (int r = 0; r < 8; r++) {
        int i = ibase + r;
        float xl = fmaxf(ix1[r], jx1), yt = fmaxf(iy1[r], jy1);
        float xr = fminf(ix2[r], jx2), yb = fminf(iy2[r], jy2);
        float iw = fmaxf(xr - xl, 0.f), ihh = fmaxf(yb - yt, 0.f);
        float inter = iw * ihh;
        bool sup = jv && (j > i) && (inter > 0.7f * (ia[r] + ja - inter));
        u64 bits = __ballot(sup);
        if (lane == 0 && i < K_SEL) maskT[(size_t)w * SEL_PAD + i] = bits;
      }
    }
  }
}

// ---------------- 6. greedy NMS: multi-wave column pull (1 block x 16 waves) ----------------
__global__ __launch_bounds__(1024) void nms_k(const u64* __restrict__ maskT,
                                              const float* __restrict__ sx1, const float* __restrict__ sy1,
                                              const float* __restrict__ sx2, const float* __restrict__ sy2,
                                              u64* __restrict__ alive_out) {
  __shared__ u64 sdiag[94 * 64];
  __shared__ u64 skept[96];
  __shared__ u64 svalid[94];
  __shared__ u64 wacc[16];
  int tid = threadIdx.x;
  int wv = tid >> 6, lane = tid & 63;

  if (tid < 96) skept[tid] = 0ull;
  for (int w = wv; w < 94; w += 16) {
    int p = w * 64 + lane;
    float bw = sx2[p] - sx1[p], bh = sy2[p] - sy1[p];
    bool ok = (p < K_SEL) && (bw >= 16.f) && (bh >= 16.f);
    u64 bits = __ballot(ok);
    if (lane == 0) svalid[w] = bits;
  }
  for (int idx = tid; idx < 94 * 64; idx += 1024) {
    int cc = idx >> 6;
    sdiag[idx] = maskT[(size_t)cc * SEL_PAD + cc * 64 + (idx & 63)];
  }
  __syncthreads();

  for (int c = 0; c < 94; c++) {
    size_t colbase = (size_t)c * SEL_PAD;
    int i0 = 2 * tid;
    ulonglong2 v0 = *(const ulonglong2*)&maskT[colbase + i0];
    ulonglong2 v1 = *(const ulonglong2*)&maskT[colbase + i0 + 2048];
    ulonglong2 v2 = *(const ulonglong2*)&maskT[colbase + i0 + 4096];
    u64 k0 = skept[i0 >> 6];
    u64 k1 = skept[(i0 + 2048) >> 6];
    u64 k2 = skept[(i0 + 4096) >> 6];
    int sh = i0 & 63;
    u64 acc = 0;
    if ((k0 >> sh) & 1) acc |= v0.x;
    if ((k0 >> (sh + 1)) & 1) acc |= v0.y;
    if ((k1 >> sh) & 1) acc |= v1.x;
    if ((k1 >> (sh + 1)) & 1) acc |= v1.y;
    if ((k2 >> sh) & 1) acc |= v2.x;
    if ((k2 >> (sh + 1)) & 1) acc |= v2.y;
    u32 lo = (u32)acc, hi = (u32)(acc >> 32);
#pragma unroll
    for (int off = 1; off < 64; off <<= 1) {
      lo |= (u32)__shfl_xor((int)lo, off, 64);
      hi |= (u32)__shfl_xor((int)hi, off, 64);
    }
    if (lane == 0) wacc[wv] = ((u64)hi << 32) | (u64)lo;
    __syncthreads();
    if (wv == 0) {
      u64 a = wacc[lane & 15];
      u32 alo = (u32)a, ahi = (u32)(a >> 32);
#pragma unroll
      for (int off = 1; off < 16; off <<= 1) {
        alo |= (u32)__shfl_xor((int)alo, off, 64);
        ahi |= (u32)__shfl_xor((int)ahi, off, 64);
      }
      u64 supp = ((u64)ahi << 32) | (u64)alo;
      u64 cur = svalid[c] & ~supp;
      u64 d = sdiag[c * 64 + lane];
      u64 rem = cur, kept = 0;
      while (rem) {
        int b = __builtin_ctzll(rem);
        kept |= (1ull << b);
        u64 dead = shfl64(d, b);
        rem &= ~dead;
        rem &= ~(1ull << b);
      }
      if (lane == 0) skept[c] = kept;
    }
    __syncthreads();
  }
  if (tid < 94) alive_out[tid] = skept[tid];
}

// ---------------- 7. finalize ----------------
__global__ __launch_bounds__(128) void final_k(const u64* __restrict__ alive,
                                               const float* __restrict__ sx1, const float* __restrict__ sy1,
                                               const float* __restrict__ sx2, const float* __restrict__ sy2,
                                               const float* __restrict__ ssc, float* __restrict__ out) {
  __shared__ u64 aw[94];
  __shared__ u32 pre[95];
  int tid = threadIdx.x;
  if (tid < 94) aw[tid] = alive[tid];
  __syncthreads();
  if (tid == 0) {
    u32 s = 0;
    for (int w = 0; w < 94; w++) { pre[w] = s; s += (u32)__popcll(aw[w]); }
    pre[94] = s;
  }
  __syncthreads();
  u32 total = pre[94];
  for (int p = tid; p < K_SEL; p += 128) {
    int w = p >> 6, b = p & 63;
    u64 word = aw[w];
    u32 kb = pre[w] + (u32)__popcll(word & ((1ull << b) - 1ull));
    bool kept = (word >> b) & 1ull;
    int slot = -1; float sc = -1.f;
    if (kept) {
      if (kb < 300) { slot = (int)kb; sc = ssc[p]; }
    } else {
      u32 s2 = total + (u32)p - kb;
      if (s2 < 300) slot = (int)s2;
    }
    if (slot >= 0) {
      out[slot * 5 + 0] = sx1[p];
      out[slot * 5 + 1] = sy1[p];
      out[slot * 5 + 2] = sx2[p];
      out[slot * 5 + 3] = sy2[p];
      out[slot * 5 + 4] = sc;
    }
  }
}

extern "C" void kernel_launch(void* const* d_in, const int* in_sizes, int n_in,
                              void* d_out, int out_size, void* d_ws, size_t ws_size,
                              hipStream_t stream) {
  const float* feat   = (const float*)d_in[0];
  const float* conv_w = (const float*)d_in[2];
  const float* conv_b = (const float*)d_in[3];
  const float* cls_w  = (const float*)d_in[4];
  const float* cls_b  = (const float*)d_in[5];
  const float* bbox_w = (const float*)d_in[6];
  const float* bbox_b = (const float*)d_in[7];
  float* out = (float*)d_out;
  char* ws = (char*)d_ws;

  float*  rpn    = (float*)(ws + OFF_RPN);
  float4* boxes  = (float4*)(ws + OFF_BOXES);
  float*  scores = (float*)(ws + OFF_SCORES);
  u64*    keys   = (u64*)(ws + OFF_KEYS);
  SelState* st   = (SelState*)(ws + OFF_STATE);
  u64*    selk   = (u64*)(ws + OFF_SELK);
  float*  sx1    = (float*)(ws + OFF_SX1);
  float*  sy1    = (float*)(ws + OFF_SY1);
  float*  sx2    = (float*)(ws + OFF_SX2);
  float*  sy2    = (float*)(ws + OFF_SY2);
  float*  ssc    = (float*)(ws + OFF_SSC);
  u64*    alive  = (u64*)(ws + OFF_ALIVE);
  u64*    maskT  = (u64*)(ws + OFF_MASKT);
  float*  wT     = (float*)(ws + OFF_WT);

  wtr_k<<<144, 256, 0, stream>>>(conv_w, wT);
  conv_k<<<800, 256, 0, stream>>>(feat, wT, conv_b, rpn);
  heads_k<<<800, 256, 0, stream>>>(rpn, cls_w, cls_b, bbox_w, bbox_b, boxes, scores, keys);
  select_k<<<1, 1024, 0, stream>>>(keys, st);
  compact_k<<<900, 256, 0, stream>>>(keys, st, selk);
  rank_k<<<94, 64, 0, stream>>>(selk, boxes, scores, sx1, sy1, sx2, sy2, ssc);
  mask_k<<<188, 256, 0, stream>>>(sx1, sy1, sx2, sy2, maskT);
  nms_k<<<1, 1024, 0, stream>>>(maskT, sx1, sy1, sx2, sy2, alive);
  final_k<<<1, 128, 0, stream>>>(alive, sx1, sy1, sx2, sy2, ssc, out);
}

// Round 10
// 1524.211 us; speedup vs baseline: 1.1828x; 1.0248x over previous
//
#include <hip/hip_runtime.h>
#include <math.h>

typedef unsigned long long u64;
typedef unsigned int u32;

#define HH 160
#define WW 160
#define CC 256
#define NPX 25600
#define NA 9
#define NSC 230400
#define K_SEL 6000
#define SEL_PAD 6016
#define IMS 2560.0f
#define DWH 4.135166556742356f

struct SelState { u64 prefix; u32 r; u32 cnt; };

// ---- ws layout (bytes) ----
#define OFF_BOXES   0u               // float4[230400] -> 3,686,400
#define OFF_SCORES  3686400u         // float [230400]
#define OFF_KEYS    4608000u         // u64   [230400]
#define OFF_STATE   7499776u
#define OFF_SELK    7500032u         // u64[6016]
#define OFF_SX1     7548160u
#define OFF_SY1     7572224u
#define OFF_SX2     7596288u
#define OFF_SY2     7620352u
#define OFF_SSC     7644416u
#define OFF_ALIVE   7668480u
#define OFF_MASKT   11503104u        // u64[94*6016 + 128 pad] -> ends 16,028,160
#define OFF_WT      16028160u        // float[2304*256] -> ends 18,387,456
#define OFF_RPN     27869184u        // float[256*160*160] -> ends 54,083,584

__constant__ float c_bx1[9] = {-91.f,-181.f,-362.f,-64.f,-128.f,-256.f,-45.f,-91.f,-181.f};
__constant__ float c_by1[9] = {-45.f,-91.f,-181.f,-64.f,-128.f,-256.f,-91.f,-181.f,-362.f};
__constant__ float c_bx2[9] = { 91.f, 181.f, 362.f, 64.f, 128.f, 256.f, 45.f, 91.f, 181.f};
__constant__ float c_by2[9] = { 45.f,  91.f, 181.f, 64.f, 128.f, 256.f, 91.f, 181.f, 362.f};

__device__ inline u64 shfl64(u64 v, int src) {
  int lo = (int)(v & 0xFFFFFFFFull), hi = (int)(v >> 32);
  lo = __shfl(lo, src, 64); hi = __shfl(hi, src, 64);
  return ((u64)(u32)hi << 32) | (u32)lo;
}

// ---------------- 0. weight transpose: w[oc][ic*9+tap] -> wT[ic*9+tap][oc] ----------------
__global__ __launch_bounds__(256) void wtr_k(const float* __restrict__ w, float* __restrict__ wT) {
  __shared__ float t[64][65];
  int kb = blockIdx.x % 36;
  int ob = blockIdx.x / 36;
  int tid = threadIdx.x;
  for (int it = 0; it < 16; it++) {
    int idx = it * 256 + tid;
    int row = idx >> 6, colk = idx & 63;
    t[row][colk] = w[(size_t)(ob * 64 + row) * 2304 + kb * 64 + colk];
  }
  __syncthreads();
  for (int it = 0; it < 16; it++) {
    int idx = it * 256 + tid;
    int krow = idx >> 6, occ = idx & 63;
    wT[(size_t)(kb * 64 + krow) * 256 + ob * 64 + occ] = t[occ][krow];
  }
}

// ---------------- 1. conv3x3 + bias + relu (scalar-weight, double-buffered ps) ----------------
// grid 800 = 5 ct x 40 rt x 4 ot. Wave = uniform 16-oc slice x 128 px.
// ps double-buffered: chunk c8+1 global loads issued before compute(c8),
// written to alternate buffer after -> staging latency hidden behind FMAs.
__global__ __launch_bounds__(256) void conv_k(const float* __restrict__ feat,
                                              const float* __restrict__ wT,
                                              const float* __restrict__ bias,
                                              float* __restrict__ outp) {
  int bx = blockIdx.x;              // 800 = 5 * 40 * 4
  int ct = bx % 5;
  int rt = (bx / 5) % 40;
  int ot = bx / 200;
  int x0 = ct * 32, y0 = rt * 4, oc0 = ot * 64;

  __shared__ float ps[2][8][6][36];

  int tid = threadIdx.x;
  int lane = tid & 63;
  int wvu = __builtin_amdgcn_readfirstlane(tid >> 6);   // wave id, SGPR-uniform
  int col = lane & 31;
  int s = lane >> 5;
  int ocw = oc0 + wvu * 16;

  // precompute staging map (constant over chunks): it 0..5 all threads, it 6 tid<96
  int s_off[7]; int s_lof[7]; bool s_val[7];
#pragma unroll
  for (int it = 0; it < 7; it++) {
    int idx = tid + it * 256;
    bool ex = (idx < 1632);
    int icl = idx / 204, rem = idx % 204;
    int r = rem / 34, c = rem % 34;
    int gy = y0 + r - 1, gx = x0 + c - 1;
    s_val[it] = ex && ((unsigned)gy < 160u) && ((unsigned)gx < 160u);
    s_off[it] = icl * NPX + gy * WW + gx;
    s_lof[it] = ex ? ((icl * 6 + r) * 36 + c) : 0;
    if (!ex) s_lof[it] = -1;
  }

  float acc0[16], acc1[16];
#pragma unroll
  for (int i = 0; i < 16; i++) { acc0[i] = 0.f; acc1[i] = 0.f; }

  float st[7];
  // stage chunk 0 into ps[0]
#pragma unroll
  for (int it = 0; it < 7; it++) {
    float v = 0.f;
    if (s_val[it]) v = feat[s_off[it]];
    if (s_lof[it] >= 0) (&ps[0][0][0][0])[s_lof[it]] = v;
  }
  __syncthreads();

  for (int c8 = 0; c8 < 32; c8++) {
    // issue global loads for next chunk (overlap with compute below)
    if (c8 < 31) {
      int icn = (c8 + 1) * 8;
#pragma unroll
      for (int it = 0; it < 7; it++) {
        st[it] = 0.f;
        if (s_val[it]) st[it] = feat[icn * NPX + s_off[it]];
      }
    }
    int buf = c8 & 1;
    int ic0 = c8 * 8;
    for (int icl = 0; icl < 8; icl++) {       // not unrolled: I-cache
      float p[4][3];
#pragma unroll
      for (int rr = 0; rr < 4; rr++)
#pragma unroll
        for (int cc = 0; cc < 3; cc++)
          p[rr][cc] = ps[buf][icl][2 * s + rr][col + cc];
      const float* wb = wT + (size_t)(ic0 + icl) * 9 * 256 + ocw;   // uniform addr
#pragma unroll
      for (int dy = 0; dy < 3; dy++) {
#pragma unroll
        for (int dx = 0; dx < 3; dx++) {
          const float* wr = wb + (dy * 3 + dx) * 256;
#pragma unroll
          for (int i = 0; i < 16; i++) {
            float wv_ = wr[i];                // s_load -> SGPR operand
            acc0[i] += wv_ * p[dy][dx];
            acc1[i] += wv_ * p[dy + 1][dx];
          }
        }
      }
    }
    if (c8 < 31) {
      __syncthreads();                        // everyone done reading ps[buf^1]
      float* dst = &ps[buf ^ 1][0][0][0];
#pragma unroll
      for (int it = 0; it < 7; it++)
        if (s_lof[it] >= 0) dst[s_lof[it]] = st[it];
      __syncthreads();                        // writes visible
    }
  }
#pragma unroll
  for (int i = 0; i < 16; i++) {
    int oc = ocw + i;
    float bv = bias[oc];
    size_t base = (size_t)oc * NPX + (y0 + 2 * s) * WW + x0 + col;
    outp[base] = fmaxf(acc0[i] + bv, 0.f);
    outp[base + WW] = fmaxf(acc1[i] + bv, 0.f);
  }
}

// ---------------- 2. heads + sigmoid + decode + clip + key ----------------
__global__ __launch_bounds__(256) void heads_k(const float* __restrict__ rpn,
                                               const float* __restrict__ cls_w,
                                               const float* __restrict__ cls_b,
                                               const float* __restrict__ bbox_w,
                                               const float* __restrict__ bbox_b,
                                               float4* __restrict__ boxes,
                                               float* __restrict__ scores,
                                               u64* __restrict__ keys) {
  __shared__ float sf[32][260];
  __shared__ float so[45][33];
  int tid = threadIdx.x;
  int px0 = blockIdx.x * 32;
  for (int idx = tid; idx < 8192; idx += 256) {
    int c = idx >> 5, p = idx & 31;
    sf[p][c] = rpn[(size_t)c * NPX + px0 + p];
  }
  __syncthreads();
  int p = tid & 31, g = tid >> 5;
  for (int oi = 0; oi < 6; oi++) {
    int o = g + oi * 8;
    if (o >= 45) break;
    const float* wr = (o < 9) ? (cls_w + o * CC) : (bbox_w + (o - 9) * CC);
    float bsum = (o < 9) ? cls_b[o] : bbox_b[o - 9];
    float s = 0.f;
    for (int c = 0; c < CC; c += 4) {
      float4 f = *(const float4*)&sf[p][c];
      float4 wv = *(const float4*)&wr[c];
      s += f.x * wv.x; s += f.y * wv.y; s += f.z * wv.z; s += f.w * wv.w;
    }
    so[o][p] = s + bsum;
  }
  __syncthreads();
  for (int t = tid; t < 288; t += 256) {
    int a = t >> 5, pp = t & 31;
    int px = px0 + pp;
    int y = px / 160, x = px - y * 160;
    float logit = so[a][pp];
    float sc = 1.f / (1.f + expf(-logit));
    float ddx = so[9 + 4 * a][pp], ddy = so[10 + 4 * a][pp];
    float ddw = fminf(so[11 + 4 * a][pp], DWH);
    float ddh = fminf(so[12 + 4 * a][pp], DWH);
    float ax1 = x * 16.f + c_bx1[a];
    float ay1 = y * 16.f + c_by1[a];
    float ax2 = x * 16.f + c_bx2[a];
    float ay2 = y * 16.f + c_by2[a];
    float aw = ax2 - ax1, ah = ay2 - ay1;
    float cx = ax1 + 0.5f * aw, cy = ay1 + 0.5f * ah;
    float pcx = ddx * aw + cx, pcy = ddy * ah + cy;
    float pw = expf(ddw) * aw, phh = expf(ddh) * ah;
    float x1 = pcx - 0.5f * pw, y1 = pcy - 0.5f * phh;
    float x2 = pcx + 0.5f * pw, y2 = pcy + 0.5f * phh;
    x1 = fminf(fmaxf(x1, 0.f), IMS); x2 = fminf(fmaxf(x2, 0.f), IMS);
    y1 = fminf(fmaxf(y1, 0.f), IMS); y2 = fminf(fmaxf(y2, 0.f), IMS);
    int gidx = px * 9 + a;
    boxes[gidx] = make_float4(x1, y1, x2, y2);
    scores[gidx] = sc;
    u32 sb = __float_as_uint(sc);
    u32 mono = (sb & 0x80000000u) ? ~sb : (sb | 0x80000000u);
    keys[gidx] = ((u64)mono << 32) | (u64)(0xFFFFFFFFu - (u32)gidx);
  }
}

// ---------------- 3. single-block radix select ----------------
// Pass 0: digits cluster (scores straddle 0.5 -> ~2-5 distinct digits/wave) =>
// ballot-dedup: one atomicAdd(popcount) per DISTINCT digit. Kills the
// same-address LDS-atomic serialization that cost ~600us. Passes 1-4: digits
// scattered/sparse -> per-lane atomics are conflict-free, keep old path.
__global__ __launch_bounds__(1024) void select_k(const u64* __restrict__ keys, SelState* st) {
  __shared__ u32 hist[8192];
  __shared__ u32 tsum[1024];
  __shared__ u32 wsum[16];
  __shared__ u64 sprefix;
  __shared__ u32 sr;
  int tid = threadIdx.x;
  int lane = tid & 63, wv = tid >> 6;
  u64 prefix = 0;
  u32 r = K_SEL;
  int bitsdone = 0;
  const int widths[5] = {13, 13, 13, 13, 12};

  for (int pass = 0; pass < 5; pass++) {
    int wbits = widths[pass];
    int nbins = 1 << wbits;
    int shift = 64 - bitsdone - wbits;
    for (int i = tid; i < nbins; i += 1024) hist[i] = 0;
    __syncthreads();

    if (pass == 0) {
#define PROC0(kk)                                                           \
      {                                                                     \
        u32 digit = (u32)((kk) >> 51);                                      \
        u64 todo = ~0ull;                                                   \
        while (todo) {                                                      \
          int src = __builtin_ctzll(todo);                                  \
          u32 d0 = (u32)__shfl((int)digit, src, 64);                        \
          u64 m = __ballot(digit == d0);                                    \
          if (lane == src) atomicAdd(&hist[d0], (u32)__popcll(m & todo));   \
          todo &= ~m;                                                       \
        }                                                                   \
      }
      int i = tid;
      for (int it = 0; it < 56; it++, i += 4096) {
        u64 k0 = keys[i];
        u64 k1 = keys[i + 1024];
        u64 k2 = keys[i + 2048];
        u64 k3 = keys[i + 3072];
        PROC0(k0) PROC0(k1) PROC0(k2) PROC0(k3)
      }
      { u64 k4 = keys[i]; PROC0(k4) }
#undef PROC0
    } else {
#define PROC(kk)                                                            \
      {                                                                     \
        bool active = (((kk) >> (64 - bitsdone)) == prefix);                \
        u32 digit = (u32)(((kk) >> shift) & (u64)(nbins - 1));              \
        u64 act = __ballot(active);                                         \
        bool done = false;                                                  \
        if (act == ~0ull) {                                                 \
          u32 d0 = (u32)__shfl((int)digit, 0, 64);                          \
          if (__ballot(digit == d0) == ~0ull) {                             \
            if (lane == 0) atomicAdd(&hist[d0], 64u);                       \
            done = true;                                                    \
          }                                                                 \
        }                                                                   \
        if (!done && active) atomicAdd(&hist[digit], 1u);                   \
      }
      int i = tid;
      for (int it = 0; it < 56; it++, i += 4096) {
        u64 k0 = keys[i];
        u64 k1 = keys[i + 1024];
        u64 k2 = keys[i + 2048];
        u64 k3 = keys[i + 3072];
        PROC(k0) PROC(k1) PROC(k2) PROC(k3)
      }
      { u64 k4 = keys[i]; PROC(k4) }
#undef PROC
    }
    __syncthreads();

    int bpt = nbins >> 10;
    u32 s = 0;
    for (int b = 0; b < bpt; b++) s += hist[tid * bpt + b];
    tsum[tid] = s;
    u32 v = s;
#pragma unroll
    for (int off = 1; off < 64; off <<= 1) v += (u32)__shfl_xor((int)v, off, 64);
    if (lane == 0) wsum[wv] = v;
    __syncthreads();

    if (tid == 0) {
      u32 cum = 0;
      int ws = 15;
      while (ws > 0 && cum + wsum[ws] < r) { cum += wsum[ws]; ws--; }
      int t = ws * 64 + 63, tend = ws * 64;
      while (t > tend && cum + tsum[t] < r) { cum += tsum[t]; t--; }
      int b = t * bpt + bpt - 1, bend = t * bpt;
      while (b > bend && cum + hist[b] < r) { cum += hist[b]; b--; }
      sprefix = (prefix << wbits) | (u64)(u32)b;
      sr = r - cum;
    }
    __syncthreads();
    prefix = sprefix;
    r = sr;
    bitsdone += wbits;
    __syncthreads();
  }
  if (tid == 0) {
    st->prefix = prefix;
    st->r = r;
    st->cnt = 0;
  }
}

__global__ __launch_bounds__(256) void compact_k(const u64* __restrict__ keys,
                                                 SelState* st, u64* __restrict__ selk) {
  int idx = blockIdx.x * 256 + threadIdx.x;
  u64 k = keys[idx];
  if (k >= st->prefix) {
    u32 pos = atomicAdd(&st->cnt, 1u);
    selk[pos] = k;
  }
}

// ---------------- 4. exact rank -> sorted SoA ----------------
__global__ __launch_bounds__(64) void rank_k(const u64* __restrict__ selk,
                                             const float4* __restrict__ boxes,
                                             const float* __restrict__ scores,
                                             float* sx1, float* sy1, float* sx2, float* sy2, float* ssc) {
  __shared__ __align__(16) u64 sk[SEL_PAD];
  int lane = threadIdx.x;
  for (int i = lane; i < SEL_PAD; i += 64) sk[i] = (i < K_SEL) ? selk[i] : 0ull;
  __syncthreads();
  int n = blockIdx.x * 64 + lane;
  u64 myk = (n < K_SEL) ? selk[n] : ~0ull;
  int cnt = 0;
  const ulonglong2* sk2 = (const ulonglong2*)sk;
  for (int j = 0; j < SEL_PAD / 2; j++) {
    ulonglong2 kk = sk2[j];
    cnt += (kk.x > myk) ? 1 : 0;
    cnt += (kk.y > myk) ? 1 : 0;
  }
  if (n < K_SEL) {
    u32 oidx = 0xFFFFFFFFu - (u32)(myk & 0xFFFFFFFFull);
    float4 b = boxes[oidx];
    sx1[cnt] = b.x; sy1[cnt] = b.y; sx2[cnt] = b.z; sy2[cnt] = b.w;
    ssc[cnt] = scores[oidx];
  }
}

// ---------------- 5. pairwise suppression mask (column-major) ----------------
__global__ __launch_bounds__(256) void mask_k(const float* __restrict__ sx1, const float* __restrict__ sy1,
                                              const float* __restrict__ sx2, const float* __restrict__ sy2,
                                              u64* __restrict__ maskT) {
  __shared__ float jb[5][3008];
  int tid = threadIdx.x;
  int wv = tid >> 6, lane = tid & 63;
  int ibase = blockIdx.x * 32 + wv * 8;
  float ix1[8], iy1[8], ix2[8], iy2[8], ia[8];
#pragma unroll
  for (int r = 0; r < 8; r++) {
    int i = ibase + r;
    ix1[r] = sx1[i]; iy1[r] = sy1[i]; ix2[r] = sx2[i]; iy2[r] = sy2[i];
    ia[r] = (ix2[r] - ix1[r]) * (iy2[r] - iy1[r]);
  }
  for (int half = 0; half < 2; half++) {
    int j0 = half * 3008;
    __syncthreads();
    for (int idx = tid; idx < 3008; idx += 256) {
      int j = j0 + idx;
      bool v = j < K_SEL;
      float a = v ? sx1[j] : 0.f;
      float b = v ? sy1[j] : 0.f;
      float c = v ? sx2[j] : 0.f;
      float d = v ? sy2[j] : 0.f;
      jb[0][idx] = a; jb[1][idx] = b; jb[2][idx] = c; jb[3][idx] = d;
      jb[4][idx] = (c - a) * (d - b);
    }
    __syncthreads();
    for (int wi = 0; wi < 47; wi++) {
      int w = half * 47 + wi;
      int jl = wi * 64 + lane;
      int j = j0 + jl;
      float jx1 = jb[0][jl], jy1 = jb[1][jl], jx2 = jb[2][jl], jy2 = jb[3][jl], ja = jb[4][jl];
      bool jv = j < K_SEL;
#pragma unroll
      for (int r = 0; r < 8; r++) {
        int i = ibase + r;
        float xl = fmaxf(ix1[r], jx1), yt = fmaxf(iy1[r], jy1);
        float xr = fminf(ix2[r], jx2), yb = fminf(iy2[r], jy2);
        float iw = fmaxf(xr - xl, 0.f), ihh = fmaxf(yb - yt, 0.f);
        float inter = iw * ihh;
        bool sup = jv && (j > i) && (inter > 0.7f * (ia[r] + ja - inter));
        u64 bits = __ballot(sup);
        if (lane == 0 && i < K_SEL) maskT[(size_t)w * SEL_PAD + i] = bits;
      }
    }
  }
}

// ---------------- 6. greedy NMS: multi-wave column pull (1 block x 16 waves) ----------------
__global__ __launch_bounds__(1024) void nms_k(const u64* __restrict__ maskT,
                                              const float* __restrict__ sx1, const float* __restrict__ sy1,
                                              const float* __restrict__ sx2, const float* __restrict__ sy2,
                                              u64* __restrict__ alive_out) {
  __shared__ u64 sdiag[94 * 64];
  __shared__ u64 skept[96];
  __shared__ u64 svalid[94];
  __shared__ u64 wacc[16];
  int tid = threadIdx.x;
  int wv = tid >> 6, lane = tid & 63;

  if (tid < 96) skept[tid] = 0ull;
  for (int w = wv; w < 94; w += 16) {
    int p = w * 64 + lane;
    float bw = sx2[p] - sx1[p], bh = sy2[p] - sy1[p];
    bool ok = (p < K_SEL) && (bw >= 16.f) && (bh >= 16.f);
    u64 bits = __ballot(ok);
    if (lane == 0) svalid[w] = bits;
  }
  for (int idx = tid; idx < 94 * 64; idx += 1024) {
    int cc = idx >> 6;
    sdiag[idx] = maskT[(size_t)cc * SEL_PAD + cc * 64 + (idx & 63)];
  }
  __syncthreads();

  for (int c = 0; c < 94; c++) {
    size_t colbase = (size_t)c * SEL_PAD;
    int i0 = 2 * tid;
    ulonglong2 v0 = *(const ulonglong2*)&maskT[colbase + i0];
    ulonglong2 v1 = *(const ulonglong2*)&maskT[colbase + i0 + 2048];
    ulonglong2 v2 = *(const ulonglong2*)&maskT[colbase + i0 + 4096];
    u64 k0 = skept[i0 >> 6];
    u64 k1 = skept[(i0 + 2048) >> 6];
    u64 k2 = skept[(i0 + 4096) >> 6];
    int sh = i0 & 63;
    u64 acc = 0;
    if ((k0 >> sh) & 1) acc |= v0.x;
    if ((k0 >> (sh + 1)) & 1) acc |= v0.y;
    if ((k1 >> sh) & 1) acc |= v1.x;
    if ((k1 >> (sh + 1)) & 1) acc |= v1.y;
    if ((k2 >> sh) & 1) acc |= v2.x;
    if ((k2 >> (sh + 1)) & 1) acc |= v2.y;
    u32 lo = (u32)acc, hi = (u32)(acc >> 32);
#pragma unroll
    for (int off = 1; off < 64; off <<= 1) {
      lo |= (u32)__shfl_xor((int)lo, off, 64);
      hi |= (u32)__shfl_xor((int)hi, off, 64);
    }
    if (lane == 0) wacc[wv] = ((u64)hi << 32) | (u64)lo;
    __syncthreads();
    if (wv == 0) {
      u64 a = wacc[lane & 15];
      u32 alo = (u32)a, ahi = (u32)(a >> 32);
#pragma unroll
      for (int off = 1; off < 16; off <<= 1) {
        alo |= (u32)__shfl_xor((int)alo, off, 64);
        ahi |= (u32)__shfl_xor((int)ahi, off, 64);
      }
      u64 supp = ((u64)ahi << 32) | (u64)alo;
      u64 cur = svalid[c] & ~supp;
      u64 d = sdiag[c * 64 + lane];
      u64 rem = cur, kept = 0;
      while (rem) {
        int b = __builtin_ctzll(rem);
        kept |= (1ull << b);
        u64 dead = shfl64(d, b);
        rem &= ~dead;
        rem &= ~(1ull << b);
      }
      if (lane == 0) skept[c] = kept;
    }
    __syncthreads();
  }
  if (tid < 94) alive_out[tid] = skept[tid];
}

// ---------------- 7. finalize ----------------
__global__ __launch_bounds__(128) void final_k(const u64* __restrict__ alive,
                                               const float* __restrict__ sx1, const float* __restrict__ sy1,
                                               const float* __restrict__ sx2, const float* __restrict__ sy2,
                                               const float* __restrict__ ssc, float* __restrict__ out) {
  __shared__ u64 aw[94];
  __shared__ u32 pre[95];
  int tid = threadIdx.x;
  if (tid < 94) aw[tid] = alive[tid];
  __syncthreads();
  if (tid == 0) {
    u32 s = 0;
    for (int w = 0; w < 94; w++) { pre[w] = s; s += (u32)__popcll(aw[w]); }
    pre[94] = s;
  }
  __syncthreads();
  u32 total = pre[94];
  for (int p = tid; p < K_SEL; p += 128) {
    int w = p >> 6, b = p & 63;
    u64 word = aw[w];
    u32 kb = pre[w] + (u32)__popcll(word & ((1ull << b) - 1ull));
    bool kept = (word >> b) & 1ull;
    int slot = -1; float sc = -1.f;
    if (kept) {
      if (kb < 300) { slot = (int)kb; sc = ssc[p]; }
    } else {
      u32 s2 = total + (u32)p - kb;
      if (s2 < 300) slot = (int)s2;
    }
    if (slot >= 0) {
      out[slot * 5 + 0] = sx1[p];
      out[slot * 5 + 1] = sy1[p];
      out[slot * 5 + 2] = sx2[p];
      out[slot * 5 + 3] = sy2[p];
      out[slot * 5 + 4] = sc;
    }
  }
}

extern "C" void kernel_launch(void* const* d_in, const int* in_sizes, int n_in,
                              void* d_out, int out_size, void* d_ws, size_t ws_size,
                              hipStream_t stream) {
  const float* feat   = (const float*)d_in[0];
  const float* conv_w = (const float*)d_in[2];
  const float* conv_b = (const float*)d_in[3];
  const float* cls_w  = (const float*)d_in[4];
  const float* cls_b  = (const float*)d_in[5];
  const float* bbox_w = (const float*)d_in[6];
  const float* bbox_b = (const float*)d_in[7];
  float* out = (float*)d_out;
  char* ws = (char*)d_ws;

  float*  rpn    = (float*)(ws + OFF_RPN);
  float4* boxes  = (float4*)(ws + OFF_BOXES);
  float*  scores = (float*)(ws + OFF_SCORES);
  u64*    keys   = (u64*)(ws + OFF_KEYS);
  SelState* st   = (SelState*)(ws + OFF_STATE);
  u64*    selk   = (u64*)(ws + OFF_SELK);
  float*  sx1    = (float*)(ws + OFF_SX1);
  float*  sy1    = (float*)(ws + OFF_SY1);
  float*  sx2    = (float*)(ws + OFF_SX2);
  float*  sy2    = (float*)(ws + OFF_SY2);
  float*  ssc    = (float*)(ws + OFF_SSC);
  u64*    alive  = (u64*)(ws + OFF_ALIVE);
  u64*    maskT  = (u64*)(ws + OFF_MASKT);
  float*  wT     = (float*)(ws + OFF_WT);

  wtr_k<<<144, 256, 0, stream>>>(conv_w, wT);
  conv_k<<<800, 256, 0, stream>>>(feat, wT, conv_b, rpn);
  heads_k<<<800, 256, 0, stream>>>(rpn, cls_w, cls_b, bbox_w, bbox_b, boxes, scores, keys);
  select_k<<<1, 1024, 0, stream>>>(keys, st);
  compact_k<<<900, 256, 0, stream>>>(keys, st, selk);
  rank_k<<<94, 64, 0, stream>>>(selk, boxes, scores, sx1, sy1, sx2, sy2, ssc);
  mask_k<<<188, 256, 0, stream>>>(sx1, sy1, sx2, sy2, maskT);
  nms_k<<<1, 1024, 0, stream>>>(maskT, sx1, sy1, sx2, sy2, alive);
  final_k<<<1, 128, 0, stream>>>(alive, sx1, sy1, sx2, sy2, ssc, out);
}